// Round 9
// baseline (1177.167 us; speedup 1.0000x reference)
//
#include <hip/hip_runtime.h>
#include <hip/hip_bf16.h>

typedef __attribute__((ext_vector_type(8))) short short8;
typedef __attribute__((ext_vector_type(4))) short short4v;
typedef __attribute__((ext_vector_type(4))) float f32x4;
using bf16 = __hip_bfloat16;

#define DEV static __device__ __forceinline__

DEV float bf2f(bf16 v) { return __bfloat162float(v); }
DEV bf16 f2bf(float v) { return __float2bfloat16(v); }
DEV float s2f(short s) {
  union { unsigned u; float f; } v;
  v.u = ((unsigned)(unsigned short)s) << 16;
  return v.f;
}
DEV short f2s(float v) {
  bf16 b = __float2bfloat16(v);
  return *(short*)&b;
}

DEV void gld_lds16(const void* g, void* l) {
  __builtin_amdgcn_global_load_lds(
      (const __attribute__((address_space(1))) void*)g,
      (__attribute__((address_space(3))) void*)l, 16, 0, 0);
}

// ---------------- weight convert+transpose: (K,N) f32 -> (N,K) bf16 ----------------
__global__ __launch_bounds__(256)
void wconv_kernel(const float* __restrict__ w, bf16* __restrict__ wT, int K, int N) {
  __shared__ float tile[32][33];
  const int kt = blockIdx.x * 32, nt = blockIdx.y * 32;
  const int tx = threadIdx.x & 31, ty = threadIdx.x >> 5;  // ty 0..7
#pragma unroll
  for (int i = 0; i < 32; i += 8)
    tile[ty + i][tx] = w[(size_t)(kt + ty + i) * N + nt + tx];
  __syncthreads();
#pragma unroll
  for (int i = 0; i < 32; i += 8)
    wT[(size_t)(nt + ty + i) * K + kt + tx] = f2bf(tile[tx][ty + i]);
}

// ---------------- LayerNorm (D=1024), f32 in -> bf16 out ----------------
__global__ __launch_bounds__(256)
void ln_kernel(const float* __restrict__ x, const float* __restrict__ g,
               const float* __restrict__ b, bf16* __restrict__ out) {
  const int row = blockIdx.x;
  const int t = threadIdx.x;
  const float4 v = ((const float4*)(x + (size_t)row * 1024))[t];
  float s = v.x + v.y + v.z + v.w;
  float ss = v.x * v.x + v.y * v.y + v.z * v.z + v.w * v.w;
#pragma unroll
  for (int off = 32; off > 0; off >>= 1) {
    s += __shfl_down(s, off);
    ss += __shfl_down(ss, off);
  }
  __shared__ float red[8];
  if ((t & 63) == 0) { red[(t >> 6) * 2] = s; red[(t >> 6) * 2 + 1] = ss; }
  __syncthreads();
  s = red[0] + red[2] + red[4] + red[6];
  ss = red[1] + red[3] + red[5] + red[7];
  const float mu = s * (1.f / 1024.f);
  const float rstd = rsqrtf(ss * (1.f / 1024.f) - mu * mu + 1e-5f);
  const float4 g4 = ((const float4*)g)[t];
  const float4 b4 = ((const float4*)b)[t];
  struct alignas(8) B4 { bf16 v[4]; } o;
  o.v[0] = f2bf((v.x - mu) * rstd * g4.x + b4.x);
  o.v[1] = f2bf((v.y - mu) * rstd * g4.y + b4.y);
  o.v[2] = f2bf((v.z - mu) * rstd * g4.z + b4.z);
  o.v[3] = f2bf((v.w - mu) * rstd * g4.w + b4.w);
  *(B4*)(out + (size_t)row * 1024 + t * 4) = o;
}

// ---------------- m97-style 128x128 bf16 MFMA GEMM, NT (A:MxK, BT:NxK) ----------------
template <int EPI>
__global__ __launch_bounds__(256, 2)
void gemm128(const bf16* __restrict__ A, const bf16* __restrict__ BT,
             const float* __restrict__ bias, const float* __restrict__ res,
             void* __restrict__ C, int M, int N, int K) {
  __shared__ short As[128 * 64];
  __shared__ short Bs[128 * 64];
  const int tid = threadIdx.x;
  const int l = tid & 63;
  const int w = tid >> 6;
  const int wr = w >> 1, wc = w & 1;

  const int nbn = N >> 7;
  const int nwg = gridDim.x;
  const int bid = blockIdx.x;
  const int q = nwg >> 3, r = nwg & 7;
  const int xcd = bid & 7, lin = bid >> 3;
  const int wg = (xcd < r ? xcd * (q + 1) : r * (q + 1) + (xcd - r) * q) + lin;
  const int bm = wg / nbn, bn = wg % nbn;

  const bf16* Ab = A + (size_t)bm * 128 * K;
  const bf16* Bb = BT + (size_t)bn * 128 * K;

  f32x4 acc[4][4];
#pragma unroll
  for (int i = 0; i < 4; ++i)
#pragma unroll
    for (int j = 0; j < 4; ++j) acc[i][j] = (f32x4){0.f, 0.f, 0.f, 0.f};

  const int srow = l >> 3;
  const int scol = (((l & 7) ^ (l >> 3)) << 3);

  for (int k0 = 0; k0 < K; k0 += 64) {
    __syncthreads();
#pragma unroll
    for (int p = 0; p < 4; ++p) {
      const int rowA = p * 32 + w * 8 + srow;
      gld_lds16(Ab + (size_t)rowA * K + k0 + scol, As + (p * 32 + w * 8) * 64);
      gld_lds16(Bb + (size_t)rowA * K + k0 + scol, Bs + (p * 32 + w * 8) * 64);
    }
    __syncthreads();
    const int xr = (l & 7) << 3;
#pragma unroll
    for (int kk = 0; kk < 2; ++kk) {
      short8 fa[4], fb[4];
#pragma unroll
      for (int m = 0; m < 4; ++m)
        fa[m] = *(const short8*)&As[(wr * 64 + m * 16 + (l & 15)) * 64 +
                                    ((kk * 32 + (l >> 4) * 8) ^ xr)];
#pragma unroll
      for (int n = 0; n < 4; ++n)
        fb[n] = *(const short8*)&Bs[(wc * 64 + n * 16 + (l & 15)) * 64 +
                                    ((kk * 32 + (l >> 4) * 8) ^ xr)];
#pragma unroll
      for (int m = 0; m < 4; ++m)
#pragma unroll
        for (int n = 0; n < 4; ++n)
          acc[m][n] = __builtin_amdgcn_mfma_f32_16x16x32_bf16(fa[m], fb[n], acc[m][n], 0, 0, 0);
    }
  }

  // epilogue: n innermost so the four 64B lane-chunks per (m,r2) are adjacent bursts
  const int lc = l & 15;
  const int lr = (l >> 4) * 4;
#pragma unroll
  for (int m = 0; m < 4; ++m) {
    const int row = bm * 128 + wr * 64 + m * 16 + lr;
#pragma unroll
    for (int r2 = 0; r2 < 4; ++r2) {
      const size_t rowoff = (size_t)(row + r2) * N;
#pragma unroll
      for (int n = 0; n < 4; ++n) {
        const int col = bn * 128 + wc * 64 + n * 16 + lc;
        float v = acc[m][n][r2] + bias[col];
        const size_t off = rowoff + col;
        if constexpr (EPI == 1) v = v / (1.f + __expf(-v));
        if constexpr (EPI == 2) {
          ((float*)C)[off] = res[off] + v;
        } else {
          ((bf16*)C)[off] = f2bf(v);
        }
      }
    }
  }
  (void)M;
}

// --- 256x256 bf16 MFMA GEMM, k-half-staggered reads (zero-extra-register overlap) ---
// 512 threads = 8 waves (2M x 4N); per-wave 128x64 (acc[8][4]); single fragment set.
// LDS = 3x32KB A + 2x32KB B = 160 KiB. Buffer indices compile-time (6-periodic).
// KEY (r9): after the k0 half-cluster (8 MFMA on fa[*][0]/fb[*][0]) those regs are
// dead -> issue the NEXT subtile's k0-half reads into them immediately, wait only the
// old k1 pair (counted lgkmcnt(2)), run k1 cluster, issue next k1-half reads. Every
// ds_read now has >= one 8-MFMA cluster + barrier before its counted wait -> LDS pipe
// (the 750cyc/K-tile floor) overlaps the MFMA pipe (620cyc) instead of serializing.
// lgkm ledger (DS ops retire in order; no SMEM/flat in flight):
//   q0 entry: 12 outstanding {fbk0:4,fak0:2 | fbk1:4,fak1:2} -> head lgkmcnt(6),
//   mid (after +2 new) lgkmcnt(2). q1/q2/q3 entry: 4 -> head/mid lgkmcnt(2).
//   q3 issues {fbk0(t+1),fak0} after k0 (mid lgkmcnt(6)) and {fbk1,fak1} after k1.
// vmcnt ledger unchanged from r8: stages A(t+2)@q0/q1, B(t+2)@q2/q3; vmcnt(6) at q2
// drains A(t+1),B(t+1) (both >=4 phases old, non-blocking), one barrier before their
// q3-tail first reads. vmcnt(0) only at tile NT-2.
template <int EPI>
__global__ __launch_bounds__(512, 2)
void gemm256(const bf16* __restrict__ A, const bf16* __restrict__ BT,
             const float* __restrict__ bias, const float* __restrict__ res,
             void* __restrict__ C, int M, int N, int K) {
  __shared__ alignas(16) short As[3][256 * 64];
  __shared__ alignas(16) short Bs[2][256 * 64];
  const int tid = threadIdx.x;
  const int l = tid & 63;
  const int w = tid >> 6;   // 0..7
  const int wr = w >> 2;    // 0..1 (M half)
  const int wc = w & 3;     // 0..3 (N quarter)

  const int nbn = N >> 8;
  const int nwg = gridDim.x;
  const int bid = blockIdx.x;
  const int q = nwg >> 3, r = nwg & 7;
  const int xcd = bid & 7, lin = bid >> 3;
  const int wg = (xcd < r ? xcd * (q + 1) : r * (q + 1) + (xcd - r) * q) + lin;
  const int bm = wg / nbn, bn = wg % nbn;

  const bf16* Ab = A + (size_t)bm * 256 * K;
  const bf16* Bb = BT + (size_t)bn * 256 * K;

  const int gcol = ((l & 7) ^ (l >> 3)) << 3;  // pre-swizzled source col (shorts)
  const int fr = l & 15;
  const int kq = (l >> 4) << 3;
  const int xr = (l & 7) << 3;
  const int k0s = kq ^ xr;
  const int k1s = (32 + kq) ^ xr;

  const bf16* Abl = Ab + (size_t)(w * 16 + (l >> 3)) * K + gcol;
  const bf16* Bbl = Bb + (size_t)(w * 16 + (l >> 3)) * K + gcol;

  f32x4 acc[8][4];
#pragma unroll
  for (int i = 0; i < 8; ++i)
#pragma unroll
    for (int j = 0; j < 4; ++j) acc[i][j] = (f32x4){0.f, 0.f, 0.f, 0.f};

  short8 fa[2][2];   // [m-pair][khalf]
  short8 fb[4][2];   // [n][khalf]

#define BARX() __builtin_amdgcn_s_barrier()
#define SBAR0() __builtin_amdgcn_sched_barrier(0)
#define LGKM0() do { asm volatile("s_waitcnt lgkmcnt(0)"); SBAR0(); } while (0)
#define LGKM2() do { asm volatile("s_waitcnt lgkmcnt(2)"); SBAR0(); } while (0)
#define LGKM6() do { asm volatile("s_waitcnt lgkmcnt(6)"); SBAR0(); } while (0)

#define STAGE_A(BUF, HALF, P)                                                      \
  do {                                                                             \
    gld_lds16((P) + (size_t)((HALF) * 128) * K,                                    \
              &As[BUF][((HALF) * 128 + w * 16) * 64]);                             \
    gld_lds16((P) + (size_t)((HALF) * 128 + 8) * K,                                \
              &As[BUF][((HALF) * 128 + w * 16 + 8) * 64]);                         \
  } while (0)

#define STAGE_B(BUF, HALF, P)                                                      \
  do {                                                                             \
    gld_lds16((P) + (size_t)((HALF) * 128) * K,                                    \
              &Bs[BUF][((HALF) * 128 + w * 16) * 64]);                             \
    gld_lds16((P) + (size_t)((HALF) * 128 + 8) * K,                                \
              &Bs[BUF][((HALF) * 128 + w * 16 + 8) * 64]);                         \
  } while (0)

  // 2 reads: one k-half of the A subtile for quadrant Q
#define RD_FA_H(BUF, Q, H)                                                               \
  do {                                                                                  \
    const int ks_ = (H) ? k1s : k0s;                                                    \
    fa[0][H] = *(const short8*)&As[BUF][(wr * 128 + (Q) * 32 + fr) * 64 + ks_];         \
    fa[1][H] = *(const short8*)&As[BUF][(wr * 128 + (Q) * 32 + 16 + fr) * 64 + ks_];    \
  } while (0)

  // 4 reads: one k-half of all four B fragments
#define RD_FB_H(BUF, H)                                                                 \
  do {                                                                                 \
    const int ks_ = (H) ? k1s : k0s;                                                   \
    _Pragma("unroll") for (int n_ = 0; n_ < 4; ++n_)                                   \
        fb[n_][H] = *(const short8*)&Bs[BUF][(wc * 64 + n_ * 16 + fr) * 64 + ks_];     \
  } while (0)

  // 8 MFMA: one k-half of quadrant Q
#define MMA_H(Q, H)                                                                    \
  do {                                                                                 \
    __builtin_amdgcn_s_setprio(1);                                                     \
    _Pragma("unroll") for (int n_ = 0; n_ < 4; ++n_) {                                 \
      acc[2 * (Q)][n_] = __builtin_amdgcn_mfma_f32_16x16x32_bf16(                      \
          fa[0][H], fb[n_][H], acc[2 * (Q)][n_], 0, 0, 0);                             \
      acc[2 * (Q) + 1][n_] = __builtin_amdgcn_mfma_f32_16x16x32_bf16(                  \
          fa[1][H], fb[n_][H], acc[2 * (Q) + 1][n_], 0, 0, 0);                         \
    }                                                                                  \
    __builtin_amdgcn_s_setprio(0);                                                     \
  } while (0)

#define TILE3(A0v, A1v, A2v, BSv, BTv, PF, NX)                                         \
  do {                                                                                 \
    /* q0: entry 12 outstanding */                                                     \
    LGKM6();                                                                           \
    MMA_H(0, 0);                                                                       \
    RD_FA_H(A0v, 1, 0);                                                                \
    SBAR0();                                                                           \
    LGKM2();                                                                           \
    MMA_H(0, 1);                                                                       \
    RD_FA_H(A0v, 1, 1);                                                                \
    if (PF) STAGE_A(A2v, 0, pfA);                                                      \
    SBAR0(); BARX();                                                                   \
    /* q1: entry 4 */                                                                  \
    LGKM2();                                                                           \
    MMA_H(1, 0);                                                                       \
    RD_FA_H(A0v, 2, 0);                                                                \
    SBAR0();                                                                           \
    LGKM2();                                                                           \
    MMA_H(1, 1);                                                                       \
    RD_FA_H(A0v, 2, 1);                                                                \
    if (PF) STAGE_A(A2v, 1, pfA);                                                      \
    SBAR0(); BARX();                                                                   \
    /* q2: entry 4 */                                                                  \
    LGKM2();                                                                           \
    MMA_H(2, 0);                                                                       \
    RD_FA_H(A0v, 3, 0);                                                                \
    SBAR0();                                                                           \
    LGKM2();                                                                           \
    MMA_H(2, 1);                                                                       \
    RD_FA_H(A0v, 3, 1);                                                                \
    if (PF) {                                                                          \
      STAGE_B(BSv, 0, pfB);                                                            \
      asm volatile("s_waitcnt vmcnt(6)" ::: "memory");                                 \
    } else if (NX) {                                                                   \
      asm volatile("s_waitcnt vmcnt(0)" ::: "memory");                                 \
    }                                                                                  \
    SBAR0(); BARX();                                                                   \
    /* q3: entry 4 */                                                                  \
    LGKM2();                                                                           \
    MMA_H(3, 0);                                                                       \
    if (NX) { RD_FB_H(BTv, 0); RD_FA_H(A1v, 0, 0); }                                   \
    SBAR0();                                                                           \
    if (NX) LGKM6(); else LGKM0();                                                     \
    MMA_H(3, 1);                                                                       \
    if (NX) { RD_FB_H(BTv, 1); RD_FA_H(A1v, 0, 1); }                                   \
    if (PF) STAGE_B(BSv, 1, pfB);                                                      \
    SBAR0();                                                                           \
    if (NX) BARX();                                                                    \
    if (PF) { pfA += 64; pfB += 64; }                                                  \
  } while (0)

  // prologue: stage A(0),B(0),A(1),B(1) (16 loads); drain tile-0's 8; establish the
  // 12-outstanding read invariant in k-half issue order.
  STAGE_A(0, 0, Abl); STAGE_A(0, 1, Abl);
  STAGE_B(0, 0, Bbl); STAGE_B(0, 1, Bbl);
  STAGE_A(1, 0, Abl + 64); STAGE_A(1, 1, Abl + 64);
  STAGE_B(1, 0, Bbl + 64); STAGE_B(1, 1, Bbl + 64);
  asm volatile("s_waitcnt vmcnt(8)" ::: "memory");
  BARX();
  RD_FB_H(0, 0);
  RD_FA_H(0, 0, 0);
  RD_FB_H(0, 1);
  RD_FA_H(0, 0, 1);
  SBAR0();

  const int NT = K >> 6;          // 16 or 64; both == 4 (mod 6), >= 10
  const int nch = (NT - 4) / 6;
  const bf16* pfA = Abl + 2 * 64;
  const bf16* pfB = Bbl + 2 * 64;
#pragma unroll 1
  for (int ch = 0; ch < nch; ++ch) {
    TILE3(0, 1, 2, 0, 1, true, true);
    TILE3(1, 2, 0, 1, 0, true, true);
    TILE3(2, 0, 1, 0, 1, true, true);
    TILE3(0, 1, 2, 1, 0, true, true);
    TILE3(1, 2, 0, 0, 1, true, true);
    TILE3(2, 0, 1, 1, 0, true, true);
  }
  // tail 4 tiles: t = NT-4 .. NT-1 (NT-4 == 0 mod 6 -> pattern restarts)
  TILE3(0, 1, 2, 0, 1, true, true);
  TILE3(1, 2, 0, 1, 0, true, true);
  TILE3(2, 0, 1, 0, 1, false, true);
  TILE3(0, 1, 2, 1, 0, false, false);

#undef BARX
#undef SBAR0
#undef LGKM0
#undef LGKM2
#undef LGKM6
#undef STAGE_A
#undef STAGE_B
#undef RD_FA_H
#undef RD_FB_H
#undef MMA_H
#undef TILE3

  // epilogue: n innermost -> four adjacent 64B chunks per (m,r2)
  const int lc = l & 15;
  const int lr = (l >> 4) * 4;
#pragma unroll
  for (int m = 0; m < 8; ++m) {
    const int row = bm * 256 + wr * 128 + m * 16 + lr;
#pragma unroll
    for (int r2 = 0; r2 < 4; ++r2) {
      const size_t rowoff = (size_t)(row + r2) * N;
#pragma unroll
      for (int n = 0; n < 4; ++n) {
        const int col = bn * 256 + wc * 64 + n * 16 + lc;
        float v = acc[m][n][r2] + bias[col];
        const size_t off = rowoff + col;
        if constexpr (EPI == 1) v = v / (1.f + __expf(-v));
        if constexpr (EPI == 2) {
          ((float*)C)[off] = res[off] + v;
        } else {
          ((bf16*)C)[off] = f2bf(v);
        }
      }
    }
  }
  (void)M;
}

// ---- per-head k/th matmuls + gate math -> a,b ; FUSED per-chunk segment scan -------
__global__ __launch_bounds__(256)
void heads_kernel(const bf16* __restrict__ piB,
                  const float* __restrict__ wz, const float* __restrict__ bz,
                  const float* __restrict__ wh, const float* __restrict__ bh,
                  bf16* __restrict__ aB, bf16* __restrict__ bB,
                  float* __restrict__ cA, float* __restrict__ cB) {
  __shared__ float wzs[4096], whs[4096];
  __shared__ float pisT[64 * 68];
  __shared__ float segA[4][64], segB[4][64];
  const int h = blockIdx.y;
  const int t0 = blockIdx.x * 64;  // global row (n*L + t)
  const int tid = threadIdx.x;
#pragma unroll
  for (int i = tid; i < 4096; i += 256) {
    wzs[i] = wz[i];
    whs[i] = wh[i];
  }
#pragma unroll
  for (int rr = 0; rr < 4; ++rr) {  // vectorized pi staging (short4), transposed store
    const int v = tid + rr * 256;   // 1024 short4 groups
    const int row = v >> 4, c4 = (v & 15) * 4;
    short4v p4 = *(const short4v*)(piB + (size_t)(t0 + row) * 1024 + h * 64 + c4);
    pisT[(c4 + 0) * 68 + row] = s2f(p4[0]);
    pisT[(c4 + 1) * 68 + row] = s2f(p4[1]);
    pisT[(c4 + 2) * 68 + row] = s2f(p4[2]);
    pisT[(c4 + 3) * 68 + row] = s2f(p4[3]);
  }
  __syncthreads();
  const int hd = tid & 63;
  const int tb = (tid >> 6) * 16;
  float accK[16], accT[16];
  const float bzv = bz[hd], bhv = bh[hd];
#pragma unroll
  for (int i = 0; i < 16; ++i) { accK[i] = bzv; accT[i] = bhv; }
  for (int j = 0; j < 64; ++j) {
    const float wzv = wzs[j * 64 + hd];
    const float whv = whs[j * 64 + hd];
    const float4* pj = (const float4*)&pisT[j * 68 + tb];
    const float4 p0 = pj[0], p1 = pj[1], p2 = pj[2], p3 = pj[3];
    float p[16] = {p0.x, p0.y, p0.z, p0.w, p1.x, p1.y, p1.z, p1.w,
                   p2.x, p2.y, p2.z, p2.w, p3.x, p3.y, p3.z, p3.w};
#pragma unroll
    for (int i = 0; i < 16; ++i) {
      accK[i] = fmaf(p[i], wzv, accK[i]);
      accT[i] = fmaf(p[i], whv, accT[i]);
    }
  }
  float As = 1.f, Bs = 0.f;
#pragma unroll
  for (int i = 0; i < 16; ++i) {
    const float k = accK[i], th = accT[i];
    const float sig = 1.f / (1.f + __expf(-k));      // sigmoid(k)
    const float a = 1.f - sig;                        // exp(-softplus(k))
    const float gg = th >= 0.f ? th + 0.5f : 1.f / (1.f + __expf(-th));  // g(th)
    const float bb = sig * gg;                        // exp(log_z + log_th)
    Bs = fmaf(a, Bs, bb);                             // t ascending within thread
    As *= a;
    const size_t idx = (size_t)(t0 + tb + i) * 1024 + h * 64 + hd;
    aB[idx] = f2bf(a);
    bB[idx] = f2bf(bb);
  }
  segA[tid >> 6][hd] = As;
  segB[tid >> 6][hd] = Bs;
  __syncthreads();
  if (tid < 64) {
    float A = segA[0][tid], B = segB[0][tid];
#pragma unroll
    for (int s = 1; s < 4; ++s) {
      B = fmaf(segA[s][tid], B, segB[s][tid]);
      A *= segA[s][tid];
    }
    const int n = t0 >> 12;
    const int chunk = (t0 >> 6) & 63;
    const size_t o = ((size_t)(n * 64 + chunk)) * 1024 + h * 64 + tid;
    cA[o] = A;
    cB[o] = B;
  }
}

// ---------------- chunk-state scan ----------------
__global__ __launch_bounds__(256)
void scan_phase2(const float* __restrict__ h0,
                 const float* __restrict__ cA, const float* __restrict__ cB,
                 float* __restrict__ hst) {
  const int idx = blockIdx.x * 256 + threadIdx.x;  // 4096
  const int c = idx & 1023;
  const int n = idx >> 10;
  float hv = h0[(size_t)n * 1024 + c];
  hv = hv >= 0.f ? hv + 0.5f : 1.f / (1.f + __expf(-hv));  // g(h0)
  for (int ch = 0; ch < 64; ++ch) {
    const size_t o = ((size_t)(n * 64 + ch)) * 1024 + c;
    hst[o] = hv;
    hv = fmaf(cA[o], hv, cB[o]);
  }
}

// ---------------- final scan pass, 8 channels/thread (short8/float4 coalesced) ------
__global__ __launch_bounds__(128)
void scan_phase3(const bf16* __restrict__ aB, const bf16* __restrict__ bB,
                 const float* __restrict__ hst,
                 float* __restrict__ rnn, bf16* __restrict__ rnnB) {
  const int idx = blockIdx.x * 128 + threadIdx.x;  // 32768
  const int c8 = idx & 127;        // channel-group of 8
  const int chunk = (idx >> 7) & 63;
  const int n = idx >> 13;
  const int c0 = c8 * 8;
  float hv[8];
  const float4* hsrc = (const float4*)(hst + ((size_t)(n * 64 + chunk)) * 1024 + c0);
  float4 ha = hsrc[0], hb = hsrc[1];
  hv[0] = ha.x; hv[1] = ha.y; hv[2] = ha.z; hv[3] = ha.w;
  hv[4] = hb.x; hv[5] = hb.y; hv[6] = hb.z; hv[7] = hb.w;
  size_t base = ((size_t)(n * 4096 + chunk * 64)) * 1024 + c0;
#pragma unroll 4
  for (int s = 0; s < 64; ++s) {
    const short8 a8 = *(const short8*)(aB + base);
    const short8 b8 = *(const short8*)(bB + base);
    short8 ob;
    float4 o0, o1;
#pragma unroll
    for (int j = 0; j < 8; ++j) {
      hv[j] = fmaf(s2f(a8[j]), hv[j], s2f(b8[j]));
      ob[j] = f2s(hv[j]);
    }
    o0.x = hv[0]; o0.y = hv[1]; o0.z = hv[2]; o0.w = hv[3];
    o1.x = hv[4]; o1.y = hv[5]; o1.z = hv[6]; o1.w = hv[7];
    ((float4*)(rnn + base))[0] = o0;
    ((float4*)(rnn + base))[1] = o1;
    *(short8*)(rnnB + base) = ob;
    base += 1024;
  }
}

// ---------------- host ----------------
extern "C" void kernel_launch(void* const* d_in, const int* in_sizes, int n_in,
                              void* d_out, int out_size, void* d_ws, size_t ws_size,
                              hipStream_t stream) {
  const float* x    = (const float*)d_in[0];
  const float* h0   = (const float*)d_in[1];
  const float* w_in = (const float*)d_in[2];
  const float* b_in = (const float*)d_in[3];
  const float* wz   = (const float*)d_in[4];
  const float* bz   = (const float*)d_in[5];
  const float* wh   = (const float*)d_in[6];
  const float* bh   = (const float*)d_in[7];
  const float* w_out= (const float*)d_in[8];
  const float* b_out= (const float*)d_in[9];
  const float* ln1g = (const float*)d_in[10];
  const float* ln1b = (const float*)d_in[11];
  const float* ln2g = (const float*)d_in[12];
  const float* ln2b = (const float*)d_in[13];
  const float* mw1  = (const float*)d_in[14];
  const float* mb1  = (const float*)d_in[15];
  const float* mw2  = (const float*)d_in[16];
  const float* mb2  = (const float*)d_in[17];
  const float* mw3  = (const float*)d_in[18];
  const float* mb3  = (const float*)d_in[19];
  (void)in_sizes; (void)n_in; (void)out_size;

  float* out0 = (float*)d_out;                       // holds xr, then x+y (in place)
  float* out1 = (float*)d_out + (size_t)16384 * 1024;  // rnn_states

  char* ws = (char*)d_ws;
  size_t o = 0;
  auto take = [&](size_t bytes) { char* p = ws + o; o += (bytes + 255) & ~(size_t)255; return p; };
  bf16* w_inT = (bf16*)take((size_t)1024 * 1024 * 2);
  bf16* w_outT= (bf16*)take((size_t)1024 * 1024 * 2);
  bf16* mw1T  = (bf16*)take((size_t)4096 * 1024 * 2);
  bf16* mw2T  = (bf16*)take((size_t)4096 * 4096 * 2);
  bf16* mw3T  = (bf16*)take((size_t)4096 * 1024 * 2);
  bf16* lnxB  = (bf16*)take((size_t)16384 * 1024 * 2);  // reused: rnnB, ln2B
  bf16* piB   = (bf16*)take((size_t)16384 * 1024 * 2);
  bf16* aB    = (bf16*)take((size_t)16384 * 1024 * 2);  // reused: t1 (chunked path)
  bf16* bB    = (bf16*)take((size_t)16384 * 1024 * 2);  // reused: t2 (chunked path)
  float* cA   = (float*)take((size_t)4 * 64 * 1024 * 4);
  float* cB   = (float*)take((size_t)4 * 64 * 1024 * 4);
  float* hst  = (float*)take((size_t)4 * 64 * 1024 * 4);
  if (o > ws_size) return;  // workspace too small -> fail loudly via wrong output

  // adaptive: full-M MLP intermediates if workspace allows
  const size_t bigbuf = (size_t)16384 * 4096 * 2;  // 128 MiB each
  bf16* t1 = aB;
  bf16* t2 = bB;
  bool big = false;
  if (o + 2 * bigbuf <= ws_size) {
    big = true;
    t1 = (bf16*)take(bigbuf);
    t2 = (bf16*)take(bigbuf);
  }

  // weights -> bf16, transposed (N,K)
  wconv_kernel<<<dim3(32, 32), 256, 0, stream>>>(w_in, w_inT, 1024, 1024);
  wconv_kernel<<<dim3(32, 32), 256, 0, stream>>>(w_out, w_outT, 1024, 1024);
  wconv_kernel<<<dim3(32, 128), 256, 0, stream>>>(mw1, mw1T, 1024, 4096);
  wconv_kernel<<<dim3(128, 128), 256, 0, stream>>>(mw2, mw2T, 4096, 4096);
  wconv_kernel<<<dim3(128, 32), 256, 0, stream>>>(mw3, mw3T, 4096, 1024);

  // LN1 -> GEMM1 (pi)
  ln_kernel<<<16384, 256, 0, stream>>>(x, ln1g, ln1b, lnxB);
  gemm256<0><<<256, 512, 0, stream>>>(lnxB, w_inT, b_in, nullptr, piB, 16384, 1024, 1024);

  // per-head gates + fused chunk-scan -> a,b,cA,cB ; chunk-state scan ; final pass
  heads_kernel<<<dim3(256, 16), 256, 0, stream>>>(piB, wz, bz, wh, bh, aB, bB, cA, cB);
  scan_phase2<<<16, 256, 0, stream>>>(h0, cA, cB, hst);
  scan_phase3<<<256, 128, 0, stream>>>(aB, bB, hst, out1, lnxB /*rnnB*/);

  // xr = x + rnn @ w_out + b_out   (written to out0)
  gemm256<2><<<256, 512, 0, stream>>>(lnxB, w_outT, b_out, x, out0, 16384, 1024, 1024);

  // LN2 -> MLP, final GEMM adds xr in place in out0
  ln_kernel<<<16384, 256, 0, stream>>>(out0, ln2g, ln2b, lnxB /*ln2B*/);
  if (big) {
    gemm256<1><<<1024, 512, 0, stream>>>(lnxB, mw1T, mb1, nullptr, t1, 16384, 4096, 1024);
    gemm256<1><<<1024, 512, 0, stream>>>(t1, mw2T, mb2, nullptr, t2, 16384, 4096, 4096);
    gemm128<2><<<1024, 256, 0, stream>>>(t2, mw3T, mb3, out0, out0, 16384, 1024, 4096);
  } else {
    for (int mc = 0; mc < 4; ++mc) {
      const bf16* a3 = lnxB + (size_t)mc * 4096 * 1024;
      gemm256<1><<<256, 512, 0, stream>>>(a3, mw1T, mb1, nullptr, t1, 4096, 4096, 1024);
      gemm256<1><<<256, 512, 0, stream>>>(t1, mw2T, mb2, nullptr, t2, 4096, 4096, 4096);
      float* oc = out0 + (size_t)mc * 4096 * 1024;
      gemm128<2><<<256, 256, 0, stream>>>(t2, mw3T, mb3, oc, oc, 4096, 1024, 4096);
    }
  }
}

// Round 10
// 1146.865 us; speedup vs baseline: 1.0264x; 1.0264x over previous
//
#include <hip/hip_runtime.h>
#include <hip/hip_bf16.h>

typedef __attribute__((ext_vector_type(8))) short short8;
typedef __attribute__((ext_vector_type(4))) short short4v;
typedef __attribute__((ext_vector_type(4))) float f32x4;
using bf16 = __hip_bfloat16;

#define DEV static __device__ __forceinline__

DEV float bf2f(bf16 v) { return __bfloat162float(v); }
DEV bf16 f2bf(float v) { return __float2bfloat16(v); }
DEV float s2f(short s) {
  union { unsigned u; float f; } v;
  v.u = ((unsigned)(unsigned short)s) << 16;
  return v.f;
}
DEV short f2s(float v) {
  bf16 b = __float2bfloat16(v);
  return *(short*)&b;
}

DEV void gld_lds16(const void* g, void* l) {
  __builtin_amdgcn_global_load_lds(
      (const __attribute__((address_space(1))) void*)g,
      (__attribute__((address_space(3))) void*)l, 16, 0, 0);
}

// ------- all weight convert+transpose in ONE launch: (K,N) f32 -> (N,K) bf16 -------
// grid = 1024 + 1024 + 4096 + 16384 + 4096 = 26624 blocks; branch is wave-uniform.
__global__ __launch_bounds__(256)
void wconv_all(const float* __restrict__ w_in, const float* __restrict__ w_out,
               const float* __restrict__ mw1, const float* __restrict__ mw2,
               const float* __restrict__ mw3,
               bf16* __restrict__ w_inT, bf16* __restrict__ w_outT,
               bf16* __restrict__ mw1T, bf16* __restrict__ mw2T,
               bf16* __restrict__ mw3T) {
  __shared__ float tile[32][33];
  const int b = blockIdx.x;
  const float* w;
  bf16* wT;
  int K, N, tb, kshift;
  if (b < 1024)       { w = w_in;  wT = w_inT;  K = 1024; N = 1024; tb = b;         kshift = 5; }
  else if (b < 2048)  { w = w_out; wT = w_outT; K = 1024; N = 1024; tb = b - 1024;  kshift = 5; }
  else if (b < 6144)  { w = mw1;   wT = mw1T;   K = 1024; N = 4096; tb = b - 2048;  kshift = 5; }
  else if (b < 22528) { w = mw2;   wT = mw2T;   K = 4096; N = 4096; tb = b - 6144;  kshift = 7; }
  else                { w = mw3;   wT = mw3T;   K = 4096; N = 1024; tb = b - 22528; kshift = 7; }
  const int kt = (tb & ((1 << kshift) - 1)) * 32;
  const int nt = (tb >> kshift) * 32;
  const int tx = threadIdx.x & 31, ty = threadIdx.x >> 5;  // ty 0..7
#pragma unroll
  for (int i = 0; i < 32; i += 8)
    tile[ty + i][tx] = w[(size_t)(kt + ty + i) * N + nt + tx];
  __syncthreads();
#pragma unroll
  for (int i = 0; i < 32; i += 8)
    wT[(size_t)(nt + ty + i) * K + kt + tx] = f2bf(tile[tx][ty + i]);
}

// ---------------- LayerNorm (D=1024), f32 in -> bf16 out ----------------
__global__ __launch_bounds__(256)
void ln_kernel(const float* __restrict__ x, const float* __restrict__ g,
               const float* __restrict__ b, bf16* __restrict__ out) {
  const int row = blockIdx.x;
  const int t = threadIdx.x;
  const float4 v = ((const float4*)(x + (size_t)row * 1024))[t];
  float s = v.x + v.y + v.z + v.w;
  float ss = v.x * v.x + v.y * v.y + v.z * v.z + v.w * v.w;
#pragma unroll
  for (int off = 32; off > 0; off >>= 1) {
    s += __shfl_down(s, off);
    ss += __shfl_down(ss, off);
  }
  __shared__ float red[8];
  if ((t & 63) == 0) { red[(t >> 6) * 2] = s; red[(t >> 6) * 2 + 1] = ss; }
  __syncthreads();
  s = red[0] + red[2] + red[4] + red[6];
  ss = red[1] + red[3] + red[5] + red[7];
  const float mu = s * (1.f / 1024.f);
  const float rstd = rsqrtf(ss * (1.f / 1024.f) - mu * mu + 1e-5f);
  const float4 g4 = ((const float4*)g)[t];
  const float4 b4 = ((const float4*)b)[t];
  struct alignas(8) B4 { bf16 v[4]; } o;
  o.v[0] = f2bf((v.x - mu) * rstd * g4.x + b4.x);
  o.v[1] = f2bf((v.y - mu) * rstd * g4.y + b4.y);
  o.v[2] = f2bf((v.z - mu) * rstd * g4.z + b4.z);
  o.v[3] = f2bf((v.w - mu) * rstd * g4.w + b4.w);
  *(B4*)(out + (size_t)row * 1024 + t * 4) = o;
}

// ---------------- m97-style 128x128 bf16 MFMA GEMM, NT (A:MxK, BT:NxK) ----------------
template <int EPI>
__global__ __launch_bounds__(256, 2)
void gemm128(const bf16* __restrict__ A, const bf16* __restrict__ BT,
             const float* __restrict__ bias, const float* __restrict__ res,
             void* __restrict__ C, int M, int N, int K) {
  __shared__ short As[128 * 64];
  __shared__ short Bs[128 * 64];
  const int tid = threadIdx.x;
  const int l = tid & 63;
  const int w = tid >> 6;
  const int wr = w >> 1, wc = w & 1;

  const int nbn = N >> 7;
  const int nwg = gridDim.x;
  const int bid = blockIdx.x;
  const int q = nwg >> 3, r = nwg & 7;
  const int xcd = bid & 7, lin = bid >> 3;
  const int wg = (xcd < r ? xcd * (q + 1) : r * (q + 1) + (xcd - r) * q) + lin;
  const int bm = wg / nbn, bn = wg % nbn;

  const bf16* Ab = A + (size_t)bm * 128 * K;
  const bf16* Bb = BT + (size_t)bn * 128 * K;

  f32x4 acc[4][4];
#pragma unroll
  for (int i = 0; i < 4; ++i)
#pragma unroll
    for (int j = 0; j < 4; ++j) acc[i][j] = (f32x4){0.f, 0.f, 0.f, 0.f};

  const int srow = l >> 3;
  const int scol = (((l & 7) ^ (l >> 3)) << 3);

  for (int k0 = 0; k0 < K; k0 += 64) {
    __syncthreads();
#pragma unroll
    for (int p = 0; p < 4; ++p) {
      const int rowA = p * 32 + w * 8 + srow;
      gld_lds16(Ab + (size_t)rowA * K + k0 + scol, As + (p * 32 + w * 8) * 64);
      gld_lds16(Bb + (size_t)rowA * K + k0 + scol, Bs + (p * 32 + w * 8) * 64);
    }
    __syncthreads();
    const int xr = (l & 7) << 3;
#pragma unroll
    for (int kk = 0; kk < 2; ++kk) {
      short8 fa[4], fb[4];
#pragma unroll
      for (int m = 0; m < 4; ++m)
        fa[m] = *(const short8*)&As[(wr * 64 + m * 16 + (l & 15)) * 64 +
                                    ((kk * 32 + (l >> 4) * 8) ^ xr)];
#pragma unroll
      for (int n = 0; n < 4; ++n)
        fb[n] = *(const short8*)&Bs[(wc * 64 + n * 16 + (l & 15)) * 64 +
                                    ((kk * 32 + (l >> 4) * 8) ^ xr)];
#pragma unroll
      for (int m = 0; m < 4; ++m)
#pragma unroll
        for (int n = 0; n < 4; ++n)
          acc[m][n] = __builtin_amdgcn_mfma_f32_16x16x32_bf16(fa[m], fb[n], acc[m][n], 0, 0, 0);
    }
  }

  // epilogue: n innermost so the four 64B lane-chunks per (m,r2) are adjacent bursts
  const int lc = l & 15;
  const int lr = (l >> 4) * 4;
#pragma unroll
  for (int m = 0; m < 4; ++m) {
    const int row = bm * 128 + wr * 64 + m * 16 + lr;
#pragma unroll
    for (int r2 = 0; r2 < 4; ++r2) {
      const size_t rowoff = (size_t)(row + r2) * N;
#pragma unroll
      for (int n = 0; n < 4; ++n) {
        const int col = bn * 128 + wc * 64 + n * 16 + lc;
        float v = acc[m][n][r2] + bias[col];
        const size_t off = rowoff + col;
        if constexpr (EPI == 1) v = v / (1.f + __expf(-v));
        if constexpr (EPI == 2) {
          ((float*)C)[off] = res[off] + v;
        } else {
          ((bf16*)C)[off] = f2bf(v);
        }
      }
    }
  }
  (void)M;
}

// ------- 256x256 bf16 MFMA GEMM, A-triple-buffered deep pipeline (r8 best) ----------
// 512 threads = 8 waves (2M x 4N); per-wave 128x64 (acc[8][4]); single fragment set.
// LDS = 3x32KB A + 2x32KB B = 160 KiB. Buffer indices compile-time (6-periodic).
// Best-measured gemm256 variant (r8: mw2 560us, MfmaUtil 41.9, total 1152).
template <int EPI>
__global__ __launch_bounds__(512, 2)
void gemm256(const bf16* __restrict__ A, const bf16* __restrict__ BT,
             const float* __restrict__ bias, const float* __restrict__ res,
             void* __restrict__ C, int M, int N, int K) {
  __shared__ alignas(16) short As[3][256 * 64];
  __shared__ alignas(16) short Bs[2][256 * 64];
  const int tid = threadIdx.x;
  const int l = tid & 63;
  const int w = tid >> 6;   // 0..7
  const int wr = w >> 2;    // 0..1 (M half)
  const int wc = w & 3;     // 0..3 (N quarter)

  const int nbn = N >> 8;
  const int nwg = gridDim.x;
  const int bid = blockIdx.x;
  const int q = nwg >> 3, r = nwg & 7;
  const int xcd = bid & 7, lin = bid >> 3;
  const int wg = (xcd < r ? xcd * (q + 1) : r * (q + 1) + (xcd - r) * q) + lin;
  const int bm = wg / nbn, bn = wg % nbn;

  const bf16* Ab = A + (size_t)bm * 256 * K;
  const bf16* Bb = BT + (size_t)bn * 256 * K;

  const int gcol = ((l & 7) ^ (l >> 3)) << 3;  // pre-swizzled source col (shorts)
  const int fr = l & 15;
  const int kq = (l >> 4) << 3;
  const int xr = (l & 7) << 3;
  const int k0s = kq ^ xr;
  const int k1s = (32 + kq) ^ xr;

  const bf16* Abl = Ab + (size_t)(w * 16 + (l >> 3)) * K + gcol;
  const bf16* Bbl = Bb + (size_t)(w * 16 + (l >> 3)) * K + gcol;

  f32x4 acc[8][4];
#pragma unroll
  for (int i = 0; i < 8; ++i)
#pragma unroll
    for (int j = 0; j < 4; ++j) acc[i][j] = (f32x4){0.f, 0.f, 0.f, 0.f};

  short8 fa[2][2];   // [m-pair][khalf]
  short8 fb[4][2];   // [n][khalf]

#define BARX() __builtin_amdgcn_s_barrier()
#define SBAR0() __builtin_amdgcn_sched_barrier(0)

#define STAGE_A(BUF, HALF, P)                                                      \
  do {                                                                             \
    gld_lds16((P) + (size_t)((HALF) * 128) * K,                                    \
              &As[BUF][((HALF) * 128 + w * 16) * 64]);                             \
    gld_lds16((P) + (size_t)((HALF) * 128 + 8) * K,                                \
              &As[BUF][((HALF) * 128 + w * 16 + 8) * 64]);                         \
  } while (0)

#define STAGE_B(BUF, HALF, P)                                                      \
  do {                                                                             \
    gld_lds16((P) + (size_t)((HALF) * 128) * K,                                    \
              &Bs[BUF][((HALF) * 128 + w * 16) * 64]);                             \
    gld_lds16((P) + (size_t)((HALF) * 128 + 8) * K,                                \
              &Bs[BUF][((HALF) * 128 + w * 16 + 8) * 64]);                         \
  } while (0)

#define RD_FA(BUF, Q)                                                                    \
  do {                                                                                  \
    fa[0][0] = *(const short8*)&As[BUF][(wr * 128 + (Q) * 32 + fr) * 64 + k0s];         \
    fa[0][1] = *(const short8*)&As[BUF][(wr * 128 + (Q) * 32 + fr) * 64 + k1s];         \
    fa[1][0] = *(const short8*)&As[BUF][(wr * 128 + (Q) * 32 + 16 + fr) * 64 + k0s];    \
    fa[1][1] = *(const short8*)&As[BUF][(wr * 128 + (Q) * 32 + 16 + fr) * 64 + k1s];    \
  } while (0)

#define RD_FB(BUF)                                                                      \
  do {                                                                                 \
    _Pragma("unroll") for (int n_ = 0; n_ < 4; ++n_) {                                 \
      fb[n_][0] = *(const short8*)&Bs[BUF][(wc * 64 + n_ * 16 + fr) * 64 + k0s];       \
      fb[n_][1] = *(const short8*)&Bs[BUF][(wc * 64 + n_ * 16 + fr) * 64 + k1s];       \
    }                                                                                  \
  } while (0)

#define MMA_Q(Q)                                                                        \
  do {                                                                                 \
    __builtin_amdgcn_s_setprio(1);                                                     \
    _Pragma("unroll") for (int n_ = 0; n_ < 4; ++n_) {                                 \
      acc[2 * (Q)][n_] = __builtin_amdgcn_mfma_f32_16x16x32_bf16(                      \
          fa[0][0], fb[n_][0], acc[2 * (Q)][n_], 0, 0, 0);                             \
      acc[2 * (Q) + 1][n_] = __builtin_amdgcn_mfma_f32_16x16x32_bf16(                  \
          fa[1][0], fb[n_][0], acc[2 * (Q) + 1][n_], 0, 0, 0);                         \
    }                                                                                  \
    _Pragma("unroll") for (int n_ = 0; n_ < 4; ++n_) {                                 \
      acc[2 * (Q)][n_] = __builtin_amdgcn_mfma_f32_16x16x32_bf16(                      \
          fa[0][1], fb[n_][1], acc[2 * (Q)][n_], 0, 0, 0);                             \
      acc[2 * (Q) + 1][n_] = __builtin_amdgcn_mfma_f32_16x16x32_bf16(                  \
          fa[1][1], fb[n_][1], acc[2 * (Q) + 1][n_], 0, 0, 0);                         \
    }                                                                                  \
    __builtin_amdgcn_s_setprio(0);                                                     \
  } while (0)

#define LGKM0() do { asm volatile("s_waitcnt lgkmcnt(0)"); SBAR0(); } while (0)

#define TILE3(A0v, A1v, A2v, BSv, BTv, PF, NX)                                         \
  do {                                                                                 \
    /* q0 */                                                                           \
    LGKM0();                                                                           \
    MMA_Q(0);                                                                          \
    if (PF) STAGE_A(A2v, 0, pfA);                                                      \
    RD_FA(A0v, 1);                                                                     \
    SBAR0(); BARX();                                                                   \
    /* q1 */                                                                           \
    LGKM0();                                                                           \
    MMA_Q(1);                                                                          \
    if (PF) STAGE_A(A2v, 1, pfA);                                                      \
    RD_FA(A0v, 2);                                                                     \
    SBAR0(); BARX();                                                                   \
    /* q2 */                                                                           \
    LGKM0();                                                                           \
    MMA_Q(2);                                                                          \
    if (PF) {                                                                          \
      STAGE_B(BSv, 0, pfB);                                                            \
      asm volatile("s_waitcnt vmcnt(6)" ::: "memory");                                 \
    } else if (NX) {                                                                   \
      asm volatile("s_waitcnt vmcnt(0)" ::: "memory");                                 \
    }                                                                                  \
    RD_FA(A0v, 3);                                                                     \
    SBAR0(); BARX();                                                                   \
    /* q3 */                                                                           \
    LGKM0();                                                                           \
    MMA_Q(3);                                                                          \
    if (PF) STAGE_B(BSv, 1, pfB);                                                      \
    if (NX) {                                                                          \
      RD_FB(BTv);                                                                      \
      RD_FA(A1v, 0);                                                                   \
      SBAR0(); BARX();                                                                 \
    }                                                                                  \
    if (PF) { pfA += 64; pfB += 64; }                                                  \
  } while (0)

  // prologue: stage A(0)->As0, B(0)->Bs0, A(1)->As1, B(1)->Bs1 (16 loads);
  // drain the 8 oldest (tile 0); pre-read tile 0 fragments.
  STAGE_A(0, 0, Abl); STAGE_A(0, 1, Abl);
  STAGE_B(0, 0, Bbl); STAGE_B(0, 1, Bbl);
  STAGE_A(1, 0, Abl + 64); STAGE_A(1, 1, Abl + 64);
  STAGE_B(1, 0, Bbl + 64); STAGE_B(1, 1, Bbl + 64);
  asm volatile("s_waitcnt vmcnt(8)" ::: "memory");
  BARX();
  RD_FB(0);
  RD_FA(0, 0);

  const int NT = K >> 6;          // 16 or 64; both == 4 (mod 6), >= 10
  const int nch = (NT - 4) / 6;
  const bf16* pfA = Abl + 2 * 64;
  const bf16* pfB = Bbl + 2 * 64;
#pragma unroll 1
  for (int ch = 0; ch < nch; ++ch) {
    TILE3(0, 1, 2, 0, 1, true, true);
    TILE3(1, 2, 0, 1, 0, true, true);
    TILE3(2, 0, 1, 0, 1, true, true);
    TILE3(0, 1, 2, 1, 0, true, true);
    TILE3(1, 2, 0, 0, 1, true, true);
    TILE3(2, 0, 1, 1, 0, true, true);
  }
  // tail 4 tiles: t = NT-4 .. NT-1 (NT-4 == 0 mod 6 -> pattern restarts)
  TILE3(0, 1, 2, 0, 1, true, true);
  TILE3(1, 2, 0, 1, 0, true, true);
  TILE3(2, 0, 1, 0, 1, false, true);
  TILE3(0, 1, 2, 1, 0, false, false);

#undef BARX
#undef SBAR0
#undef STAGE_A
#undef STAGE_B
#undef RD_FA
#undef RD_FB
#undef MMA_Q
#undef LGKM0
#undef TILE3

  // epilogue: n innermost -> four adjacent 64B chunks per (m,r2)
  const int lc = l & 15;
  const int lr = (l >> 4) * 4;
#pragma unroll
  for (int m = 0; m < 8; ++m) {
    const int row = bm * 256 + wr * 128 + m * 16 + lr;
#pragma unroll
    for (int r2 = 0; r2 < 4; ++r2) {
      const size_t rowoff = (size_t)(row + r2) * N;
#pragma unroll
      for (int n = 0; n < 4; ++n) {
        const int col = bn * 256 + wc * 64 + n * 16 + lc;
        float v = acc[m][n][r2] + bias[col];
        const size_t off = rowoff + col;
        if constexpr (EPI == 1) v = v / (1.f + __expf(-v));
        if constexpr (EPI == 2) {
          ((float*)C)[off] = res[off] + v;
        } else {
          ((bf16*)C)[off] = f2bf(v);
        }
      }
    }
  }
  (void)M;
}

// ---- per-head k/th matmuls + gate math -> a,b ; FUSED per-chunk segment scan -------
__global__ __launch_bounds__(256)
void heads_kernel(const bf16* __restrict__ piB,
                  const float* __restrict__ wz, const float* __restrict__ bz,
                  const float* __restrict__ wh, const float* __restrict__ bh,
                  bf16* __restrict__ aB, bf16* __restrict__ bB,
                  float* __restrict__ cA, float* __restrict__ cB) {
  __shared__ float wzs[4096], whs[4096];
  __shared__ float pisT[64 * 68];
  __shared__ float segA[4][64], segB[4][64];
  const int h = blockIdx.y;
  const int t0 = blockIdx.x * 64;  // global row (n*L + t)
  const int tid = threadIdx.x;
#pragma unroll
  for (int i = tid; i < 4096; i += 256) {
    wzs[i] = wz[i];
    whs[i] = wh[i];
  }
#pragma unroll
  for (int rr = 0; rr < 4; ++rr) {  // vectorized pi staging (short4), transposed store
    const int v = tid + rr * 256;   // 1024 short4 groups
    const int row = v >> 4, c4 = (v & 15) * 4;
    short4v p4 = *(const short4v*)(piB + (size_t)(t0 + row) * 1024 + h * 64 + c4);
    pisT[(c4 + 0) * 68 + row] = s2f(p4[0]);
    pisT[(c4 + 1) * 68 + row] = s2f(p4[1]);
    pisT[(c4 + 2) * 68 + row] = s2f(p4[2]);
    pisT[(c4 + 3) * 68 + row] = s2f(p4[3]);
  }
  __syncthreads();
  const int hd = tid & 63;
  const int tb = (tid >> 6) * 16;
  float accK[16], accT[16];
  const float bzv = bz[hd], bhv = bh[hd];
#pragma unroll
  for (int i = 0; i < 16; ++i) { accK[i] = bzv; accT[i] = bhv; }
  for (int j = 0; j < 64; ++j) {
    const float wzv = wzs[j * 64 + hd];
    const float whv = whs[j * 64 + hd];
    const float4* pj = (const float4*)&pisT[j * 68 + tb];
    const float4 p0 = pj[0], p1 = pj[1], p2 = pj[2], p3 = pj[3];
    float p[16] = {p0.x, p0.y, p0.z, p0.w, p1.x, p1.y, p1.z, p1.w,
                   p2.x, p2.y, p2.z, p2.w, p3.x, p3.y, p3.z, p3.w};
#pragma unroll
    for (int i = 0; i < 16; ++i) {
      accK[i] = fmaf(p[i], wzv, accK[i]);
      accT[i] = fmaf(p[i], whv, accT[i]);
    }
  }
  float As = 1.f, Bs = 0.f;
#pragma unroll
  for (int i = 0; i < 16; ++i) {
    const float k = accK[i], th = accT[i];
    const float sig = 1.f / (1.f + __expf(-k));      // sigmoid(k)
    const float a = 1.f - sig;                        // exp(-softplus(k))
    const float gg = th >= 0.f ? th + 0.5f : 1.f / (1.f + __expf(-th));  // g(th)
    const float bb = sig * gg;                        // exp(log_z + log_th)
    Bs = fmaf(a, Bs, bb);                             // t ascending within thread
    As *= a;
    const size_t idx = (size_t)(t0 + tb + i) * 1024 + h * 64 + hd;
    aB[idx] = f2bf(a);
    bB[idx] = f2bf(bb);
  }
  segA[tid >> 6][hd] = As;
  segB[tid >> 6][hd] = Bs;
  __syncthreads();
  if (tid < 64) {
    float A = segA[0][tid], B = segB[0][tid];
#pragma unroll
    for (int s = 1; s < 4; ++s) {
      B = fmaf(segA[s][tid], B, segB[s][tid]);
      A *= segA[s][tid];
    }
    const int n = t0 >> 12;
    const int chunk = (t0 >> 6) & 63;
    const size_t o = ((size_t)(n * 64 + chunk)) * 1024 + h * 64 + tid;
    cA[o] = A;
    cB[o] = B;
  }
}

// ---------------- chunk-state scan ----------------
__global__ __launch_bounds__(256)
void scan_phase2(const float* __restrict__ h0,
                 const float* __restrict__ cA, const float* __restrict__ cB,
                 float* __restrict__ hst) {
  const int idx = blockIdx.x * 256 + threadIdx.x;  // 4096
  const int c = idx & 1023;
  const int n = idx >> 10;
  float hv = h0[(size_t)n * 1024 + c];
  hv = hv >= 0.f ? hv + 0.5f : 1.f / (1.f + __expf(-hv));  // g(h0)
  for (int ch = 0; ch < 64; ++ch) {
    const size_t o = ((size_t)(n * 64 + ch)) * 1024 + c;
    hst[o] = hv;
    hv = fmaf(cA[o], hv, cB[o]);
  }
}

// ---------------- final scan pass, 8 channels/thread (short8/float4 coalesced) ------
__global__ __launch_bounds__(128)
void scan_phase3(const bf16* __restrict__ aB, const bf16* __restrict__ bB,
                 const float* __restrict__ hst,
                 float* __restrict__ rnn, bf16* __restrict__ rnnB) {
  const int idx = blockIdx.x * 128 + threadIdx.x;  // 32768
  const int c8 = idx & 127;        // channel-group of 8
  const int chunk = (idx >> 7) & 63;
  const int n = idx >> 13;
  const int c0 = c8 * 8;
  float hv[8];
  const float4* hsrc = (const float4*)(hst + ((size_t)(n * 64 + chunk)) * 1024 + c0);
  float4 ha = hsrc[0], hb = hsrc[1];
  hv[0] = ha.x; hv[1] = ha.y; hv[2] = ha.z; hv[3] = ha.w;
  hv[4] = hb.x; hv[5] = hb.y; hv[6] = hb.z; hv[7] = hb.w;
  size_t base = ((size_t)(n * 4096 + chunk * 64)) * 1024 + c0;
#pragma unroll 4
  for (int s = 0; s < 64; ++s) {
    const short8 a8 = *(const short8*)(aB + base);
    const short8 b8 = *(const short8*)(bB + base);
    short8 ob;
    float4 o0, o1;
#pragma unroll
    for (int j = 0; j < 8; ++j) {
      hv[j] = fmaf(s2f(a8[j]), hv[j], s2f(b8[j]));
      ob[j] = f2s(hv[j]);
    }
    o0.x = hv[0]; o0.y = hv[1]; o0.z = hv[2]; o0.w = hv[3];
    o1.x = hv[4]; o1.y = hv[5]; o1.z = hv[6]; o1.w = hv[7];
    ((float4*)(rnn + base))[0] = o0;
    ((float4*)(rnn + base))[1] = o1;
    *(short8*)(rnnB + base) = ob;
    base += 1024;
  }
}

// ---------------- host ----------------
extern "C" void kernel_launch(void* const* d_in, const int* in_sizes, int n_in,
                              void* d_out, int out_size, void* d_ws, size_t ws_size,
                              hipStream_t stream) {
  const float* x    = (const float*)d_in[0];
  const float* h0   = (const float*)d_in[1];
  const float* w_in = (const float*)d_in[2];
  const float* b_in = (const float*)d_in[3];
  const float* wz   = (const float*)d_in[4];
  const float* bz   = (const float*)d_in[5];
  const float* wh   = (const float*)d_in[6];
  const float* bh   = (const float*)d_in[7];
  const float* w_out= (const float*)d_in[8];
  const float* b_out= (const float*)d_in[9];
  const float* ln1g = (const float*)d_in[10];
  const float* ln1b = (const float*)d_in[11];
  const float* ln2g = (const float*)d_in[12];
  const float* ln2b = (const float*)d_in[13];
  const float* mw1  = (const float*)d_in[14];
  const float* mb1  = (const float*)d_in[15];
  const float* mw2  = (const float*)d_in[16];
  const float* mb2  = (const float*)d_in[17];
  const float* mw3  = (const float*)d_in[18];
  const float* mb3  = (const float*)d_in[19];
  (void)in_sizes; (void)n_in; (void)out_size;

  float* out0 = (float*)d_out;                       // holds xr, then x+y (in place)
  float* out1 = (float*)d_out + (size_t)16384 * 1024;  // rnn_states

  char* ws = (char*)d_ws;
  size_t o = 0;
  auto take = [&](size_t bytes) { char* p = ws + o; o += (bytes + 255) & ~(size_t)255; return p; };
  bf16* w_inT = (bf16*)take((size_t)1024 * 1024 * 2);
  bf16* w_outT= (bf16*)take((size_t)1024 * 1024 * 2);
  bf16* mw1T  = (bf16*)take((size_t)4096 * 1024 * 2);
  bf16* mw2T  = (bf16*)take((size_t)4096 * 4096 * 2);
  bf16* mw3T  = (bf16*)take((size_t)4096 * 1024 * 2);
  bf16* lnxB  = (bf16*)take((size_t)16384 * 1024 * 2);  // reused: rnnB, ln2B
  bf16* piB   = (bf16*)take((size_t)16384 * 1024 * 2);
  bf16* aB    = (bf16*)take((size_t)16384 * 1024 * 2);  // reused: t1 (chunked path)
  bf16* bB    = (bf16*)take((size_t)16384 * 1024 * 2);  // reused: t2 (chunked path)
  float* cA   = (float*)take((size_t)4 * 64 * 1024 * 4);
  float* cB   = (float*)take((size_t)4 * 64 * 1024 * 4);
  float* hst  = (float*)take((size_t)4 * 64 * 1024 * 4);
  if (o > ws_size) return;  // workspace too small -> fail loudly via wrong output

  // adaptive: full-M MLP intermediates if workspace allows
  const size_t bigbuf = (size_t)16384 * 4096 * 2;  // 128 MiB each
  bf16* t1 = aB;
  bf16* t2 = bB;
  bool big = false;
  if (o + 2 * bigbuf <= ws_size) {
    big = true;
    t1 = (bf16*)take(bigbuf);
    t2 = (bf16*)take(bigbuf);
  }

  // all weights -> bf16 transposed, one launch
  wconv_all<<<26624, 256, 0, stream>>>(w_in, w_out, mw1, mw2, mw3,
                                       w_inT, w_outT, mw1T, mw2T, mw3T);

  // LN1 -> GEMM1 (pi)
  ln_kernel<<<16384, 256, 0, stream>>>(x, ln1g, ln1b, lnxB);
  gemm256<0><<<256, 512, 0, stream>>>(lnxB, w_inT, b_in, nullptr, piB, 16384, 1024, 1024);

  // per-head gates + fused chunk-scan -> a,b,cA,cB ; chunk-state scan ; final pass
  heads_kernel<<<dim3(256, 16), 256, 0, stream>>>(piB, wz, bz, wh, bh, aB, bB, cA, cB);
  scan_phase2<<<16, 256, 0, stream>>>(h0, cA, cB, hst);
  scan_phase3<<<256, 128, 0, stream>>>(aB, bB, hst, out1, lnxB /*rnnB*/);

  // xr = x + rnn @ w_out + b_out   (written to out0)
  gemm256<2><<<256, 512, 0, stream>>>(lnxB, w_outT, b_out, x, out0, 16384, 1024, 1024);

  // LN2 -> MLP, final GEMM adds xr in place in out0
  ln_kernel<<<16384, 256, 0, stream>>>(out0, ln2g, ln2b, lnxB /*ln2B*/);
  if (big) {
    gemm256<1><<<1024, 512, 0, stream>>>(lnxB, mw1T, mb1, nullptr, t1, 16384, 4096, 1024);
    gemm256<1><<<1024, 512, 0, stream>>>(t1, mw2T, mb2, nullptr, t2, 16384, 4096, 4096);
    gemm128<2><<<1024, 256, 0, stream>>>(t2, mw3T, mb3, out0, out0, 16384, 1024, 4096);
  } else {
    for (int mc = 0; mc < 4; ++mc) {
      const bf16* a3 = lnxB + (size_t)mc * 4096 * 1024;
      gemm256<1><<<256, 512, 0, stream>>>(a3, mw1T, mb1, nullptr, t1, 4096, 4096, 1024);
      gemm256<1><<<256, 512, 0, stream>>>(t1, mw2T, mb2, nullptr, t2, 4096, 4096, 4096);
      float* oc = out0 + (size_t)mc * 4096 * 1024;
      gemm128<2><<<256, 256, 0, stream>>>(t2, mw3T, mb3, oc, oc, 4096, 1024, 4096);
    }
  }
}

// Round 11
// 1130.821 us; speedup vs baseline: 1.0410x; 1.0142x over previous
//
#include <hip/hip_runtime.h>
#include <hip/hip_bf16.h>

typedef __attribute__((ext_vector_type(8))) short short8;
typedef __attribute__((ext_vector_type(4))) short short4v;
typedef __attribute__((ext_vector_type(4))) float f32x4;
using bf16 = __hip_bfloat16;

#define DEV static __device__ __forceinline__

DEV float bf2f(bf16 v) { return __bfloat162float(v); }
DEV bf16 f2bf(float v) { return __float2bfloat16(v); }
DEV float s2f(short s) {
  union { unsigned u; float f; } v;
  v.u = ((unsigned)(unsigned short)s) << 16;
  return v.f;
}
DEV short f2s(float v) {
  bf16 b = __float2bfloat16(v);
  return *(short*)&b;
}

DEV void gld_lds16(const void* g, void* l) {
  __builtin_amdgcn_global_load_lds(
      (const __attribute__((address_space(1))) void*)g,
      (__attribute__((address_space(3))) void*)l, 16, 0, 0);
}

// ------- all weight convert+transpose in ONE launch: (K,N) f32 -> (N,K) bf16 -------
// grid = 1024 + 1024 + 4096 + 16384 + 4096 = 26624 blocks; branch is wave-uniform.
__global__ __launch_bounds__(256)
void wconv_all(const float* __restrict__ w_in, const float* __restrict__ w_out,
               const float* __restrict__ mw1, const float* __restrict__ mw2,
               const float* __restrict__ mw3,
               bf16* __restrict__ w_inT, bf16* __restrict__ w_outT,
               bf16* __restrict__ mw1T, bf16* __restrict__ mw2T,
               bf16* __restrict__ mw3T) {
  __shared__ float tile[32][33];
  const int b = blockIdx.x;
  const float* w;
  bf16* wT;
  int K, N, tb, kshift;
  if (b < 1024)       { w = w_in;  wT = w_inT;  K = 1024; N = 1024; tb = b;         kshift = 5; }
  else if (b < 2048)  { w = w_out; wT = w_outT; K = 1024; N = 1024; tb = b - 1024;  kshift = 5; }
  else if (b < 6144)  { w = mw1;   wT = mw1T;   K = 1024; N = 4096; tb = b - 2048;  kshift = 5; }
  else if (b < 22528) { w = mw2;   wT = mw2T;   K = 4096; N = 4096; tb = b - 6144;  kshift = 7; }
  else                { w = mw3;   wT = mw3T;   K = 4096; N = 1024; tb = b - 22528; kshift = 7; }
  const int kt = (tb & ((1 << kshift) - 1)) * 32;
  const int nt = (tb >> kshift) * 32;
  const int tx = threadIdx.x & 31, ty = threadIdx.x >> 5;  // ty 0..7
#pragma unroll
  for (int i = 0; i < 32; i += 8)
    tile[ty + i][tx] = w[(size_t)(kt + ty + i) * N + nt + tx];
  __syncthreads();
#pragma unroll
  for (int i = 0; i < 32; i += 8)
    wT[(size_t)(nt + ty + i) * K + kt + tx] = f2bf(tile[tx][ty + i]);
}

// ---------------- LayerNorm (D=1024), f32 in -> bf16 out ----------------
__global__ __launch_bounds__(256)
void ln_kernel(const float* __restrict__ x, const float* __restrict__ g,
               const float* __restrict__ b, bf16* __restrict__ out) {
  const int row = blockIdx.x;
  const int t = threadIdx.x;
  const float4 v = ((const float4*)(x + (size_t)row * 1024))[t];
  float s = v.x + v.y + v.z + v.w;
  float ss = v.x * v.x + v.y * v.y + v.z * v.z + v.w * v.w;
#pragma unroll
  for (int off = 32; off > 0; off >>= 1) {
    s += __shfl_down(s, off);
    ss += __shfl_down(ss, off);
  }
  __shared__ float red[8];
  if ((t & 63) == 0) { red[(t >> 6) * 2] = s; red[(t >> 6) * 2 + 1] = ss; }
  __syncthreads();
  s = red[0] + red[2] + red[4] + red[6];
  ss = red[1] + red[3] + red[5] + red[7];
  const float mu = s * (1.f / 1024.f);
  const float rstd = rsqrtf(ss * (1.f / 1024.f) - mu * mu + 1e-5f);
  const float4 g4 = ((const float4*)g)[t];
  const float4 b4 = ((const float4*)b)[t];
  struct alignas(8) B4 { bf16 v[4]; } o;
  o.v[0] = f2bf((v.x - mu) * rstd * g4.x + b4.x);
  o.v[1] = f2bf((v.y - mu) * rstd * g4.y + b4.y);
  o.v[2] = f2bf((v.z - mu) * rstd * g4.z + b4.z);
  o.v[3] = f2bf((v.w - mu) * rstd * g4.w + b4.w);
  *(B4*)(out + (size_t)row * 1024 + t * 4) = o;
}

// ---------------- m97-style 128x128 bf16 MFMA GEMM, NT (A:MxK, BT:NxK) ----------------
// kept only for the small-workspace fallback path
template <int EPI>
__global__ __launch_bounds__(256, 2)
void gemm128(const bf16* __restrict__ A, const bf16* __restrict__ BT,
             const float* __restrict__ bias, const float* __restrict__ res,
             void* __restrict__ C, int M, int N, int K) {
  __shared__ short As[128 * 64];
  __shared__ short Bs[128 * 64];
  const int tid = threadIdx.x;
  const int l = tid & 63;
  const int w = tid >> 6;
  const int wr = w >> 1, wc = w & 1;

  const int nbn = N >> 7;
  const int nwg = gridDim.x;
  const int bid = blockIdx.x;
  const int q = nwg >> 3, r = nwg & 7;
  const int xcd = bid & 7, lin = bid >> 3;
  const int wg = (xcd < r ? xcd * (q + 1) : r * (q + 1) + (xcd - r) * q) + lin;
  const int bm = wg / nbn, bn = wg % nbn;

  const bf16* Ab = A + (size_t)bm * 128 * K;
  const bf16* Bb = BT + (size_t)bn * 128 * K;

  f32x4 acc[4][4];
#pragma unroll
  for (int i = 0; i < 4; ++i)
#pragma unroll
    for (int j = 0; j < 4; ++j) acc[i][j] = (f32x4){0.f, 0.f, 0.f, 0.f};

  const int srow = l >> 3;
  const int scol = (((l & 7) ^ (l >> 3)) << 3);

  for (int k0 = 0; k0 < K; k0 += 64) {
    __syncthreads();
#pragma unroll
    for (int p = 0; p < 4; ++p) {
      const int rowA = p * 32 + w * 8 + srow;
      gld_lds16(Ab + (size_t)rowA * K + k0 + scol, As + (p * 32 + w * 8) * 64);
      gld_lds16(Bb + (size_t)rowA * K + k0 + scol, Bs + (p * 32 + w * 8) * 64);
    }
    __syncthreads();
    const int xr = (l & 7) << 3;
#pragma unroll
    for (int kk = 0; kk < 2; ++kk) {
      short8 fa[4], fb[4];
#pragma unroll
      for (int m = 0; m < 4; ++m)
        fa[m] = *(const short8*)&As[(wr * 64 + m * 16 + (l & 15)) * 64 +
                                    ((kk * 32 + (l >> 4) * 8) ^ xr)];
#pragma unroll
      for (int n = 0; n < 4; ++n)
        fb[n] = *(const short8*)&Bs[(wc * 64 + n * 16 + (l & 15)) * 64 +
                                    ((kk * 32 + (l >> 4) * 8) ^ xr)];
#pragma unroll
      for (int m = 0; m < 4; ++m)
#pragma unroll
        for (int n = 0; n < 4; ++n)
          acc[m][n] = __builtin_amdgcn_mfma_f32_16x16x32_bf16(fa[m], fb[n], acc[m][n], 0, 0, 0);
    }
  }

  // epilogue: n innermost so the four 64B lane-chunks per (m,r2) are adjacent bursts
  const int lc = l & 15;
  const int lr = (l >> 4) * 4;
#pragma unroll
  for (int m = 0; m < 4; ++m) {
    const int row = bm * 128 + wr * 64 + m * 16 + lr;
#pragma unroll
    for (int r2 = 0; r2 < 4; ++r2) {
      const size_t rowoff = (size_t)(row + r2) * N;
#pragma unroll
      for (int n = 0; n < 4; ++n) {
        const int col = bn * 128 + wc * 64 + n * 16 + lc;
        float v = acc[m][n][r2] + bias[col];
        const size_t off = rowoff + col;
        if constexpr (EPI == 1) v = v / (1.f + __expf(-v));
        if constexpr (EPI == 2) {
          ((float*)C)[off] = res[off] + v;
        } else {
          ((bf16*)C)[off] = f2bf(v);
        }
      }
    }
  }
  (void)M;
}

// ------- 256x256 bf16 MFMA GEMM, A-triple-buffered deep pipeline (r8 best) ----------
// 512 threads = 8 waves (2M x 4N); per-wave 128x64 (acc[8][4]); single fragment set.
// LDS = 3x32KB A + 2x32KB B = 160 KiB. Buffer indices compile-time (6-periodic).
// Best-measured gemm256 variant (r8/r10: mw2 556us, MfmaUtil 42.7).
// NOTE (session record): six schedule variants (8-phase, reg-dbuf, sched-pins,
// tail-read, triple-buf-A, k-half stagger) all measure 41-44% MfmaUtil at this
// shape; this is the plateau of blind source-level scheduling on this structure.
template <int EPI>
__global__ __launch_bounds__(512, 2)
void gemm256(const bf16* __restrict__ A, const bf16* __restrict__ BT,
             const float* __restrict__ bias, const float* __restrict__ res,
             void* __restrict__ C, int M, int N, int K) {
  __shared__ alignas(16) short As[3][256 * 64];
  __shared__ alignas(16) short Bs[2][256 * 64];
  const int tid = threadIdx.x;
  const int l = tid & 63;
  const int w = tid >> 6;   // 0..7
  const int wr = w >> 2;    // 0..1 (M half)
  const int wc = w & 3;     // 0..3 (N quarter)

  const int nbn = N >> 8;
  const int nwg = gridDim.x;
  const int bid = blockIdx.x;
  const int q = nwg >> 3, r = nwg & 7;
  const int xcd = bid & 7, lin = bid >> 3;
  const int wg = (xcd < r ? xcd * (q + 1) : r * (q + 1) + (xcd - r) * q) + lin;
  const int bm = wg / nbn, bn = wg % nbn;

  const bf16* Ab = A + (size_t)bm * 256 * K;
  const bf16* Bb = BT + (size_t)bn * 256 * K;

  const int gcol = ((l & 7) ^ (l >> 3)) << 3;  // pre-swizzled source col (shorts)
  const int fr = l & 15;
  const int kq = (l >> 4) << 3;
  const int xr = (l & 7) << 3;
  const int k0s = kq ^ xr;
  const int k1s = (32 + kq) ^ xr;

  const bf16* Abl = Ab + (size_t)(w * 16 + (l >> 3)) * K + gcol;
  const bf16* Bbl = Bb + (size_t)(w * 16 + (l >> 3)) * K + gcol;

  f32x4 acc[8][4];
#pragma unroll
  for (int i = 0; i < 8; ++i)
#pragma unroll
    for (int j = 0; j < 4; ++j) acc[i][j] = (f32x4){0.f, 0.f, 0.f, 0.f};

  short8 fa[2][2];   // [m-pair][khalf]
  short8 fb[4][2];   // [n][khalf]

#define BARX() __builtin_amdgcn_s_barrier()
#define SBAR0() __builtin_amdgcn_sched_barrier(0)

#define STAGE_A(BUF, HALF, P)                                                      \
  do {                                                                             \
    gld_lds16((P) + (size_t)((HALF) * 128) * K,                                    \
              &As[BUF][((HALF) * 128 + w * 16) * 64]);                             \
    gld_lds16((P) + (size_t)((HALF) * 128 + 8) * K,                                \
              &As[BUF][((HALF) * 128 + w * 16 + 8) * 64]);                         \
  } while (0)

#define STAGE_B(BUF, HALF, P)                                                      \
  do {                                                                             \
    gld_lds16((P) + (size_t)((HALF) * 128) * K,                                    \
              &Bs[BUF][((HALF) * 128 + w * 16) * 64]);                             \
    gld_lds16((P) + (size_t)((HALF) * 128 + 8) * K,                                \
              &Bs[BUF][((HALF) * 128 + w * 16 + 8) * 64]);                         \
  } while (0)

#define RD_FA(BUF, Q)                                                                    \
  do {                                                                                  \
    fa[0][0] = *(const short8*)&As[BUF][(wr * 128 + (Q) * 32 + fr) * 64 + k0s];         \
    fa[0][1] = *(const short8*)&As[BUF][(wr * 128 + (Q) * 32 + fr) * 64 + k1s];         \
    fa[1][0] = *(const short8*)&As[BUF][(wr * 128 + (Q) * 32 + 16 + fr) * 64 + k0s];    \
    fa[1][1] = *(const short8*)&As[BUF][(wr * 128 + (Q) * 32 + 16 + fr) * 64 + k1s];    \
  } while (0)

#define RD_FB(BUF)                                                                      \
  do {                                                                                 \
    _Pragma("unroll") for (int n_ = 0; n_ < 4; ++n_) {                                 \
      fb[n_][0] = *(const short8*)&Bs[BUF][(wc * 64 + n_ * 16 + fr) * 64 + k0s];       \
      fb[n_][1] = *(const short8*)&Bs[BUF][(wc * 64 + n_ * 16 + fr) * 64 + k1s];       \
    }                                                                                  \
  } while (0)

#define MMA_Q(Q)                                                                        \
  do {                                                                                 \
    __builtin_amdgcn_s_setprio(1);                                                     \
    _Pragma("unroll") for (int n_ = 0; n_ < 4; ++n_) {                                 \
      acc[2 * (Q)][n_] = __builtin_amdgcn_mfma_f32_16x16x32_bf16(                      \
          fa[0][0], fb[n_][0], acc[2 * (Q)][n_], 0, 0, 0);                             \
      acc[2 * (Q) + 1][n_] = __builtin_amdgcn_mfma_f32_16x16x32_bf16(                  \
          fa[1][0], fb[n_][0], acc[2 * (Q) + 1][n_], 0, 0, 0);                         \
    }                                                                                  \
    _Pragma("unroll") for (int n_ = 0; n_ < 4; ++n_) {                                 \
      acc[2 * (Q)][n_] = __builtin_amdgcn_mfma_f32_16x16x32_bf16(                      \
          fa[0][1], fb[n_][1], acc[2 * (Q)][n_], 0, 0, 0);                             \
      acc[2 * (Q) + 1][n_] = __builtin_amdgcn_mfma_f32_16x16x32_bf16(                  \
          fa[1][1], fb[n_][1], acc[2 * (Q) + 1][n_], 0, 0, 0);                         \
    }                                                                                  \
    __builtin_amdgcn_s_setprio(0);                                                     \
  } while (0)

#define LGKM0() do { asm volatile("s_waitcnt lgkmcnt(0)"); SBAR0(); } while (0)

#define TILE3(A0v, A1v, A2v, BSv, BTv, PF, NX)                                         \
  do {                                                                                 \
    /* q0 */                                                                           \
    LGKM0();                                                                           \
    MMA_Q(0);                                                                          \
    if (PF) STAGE_A(A2v, 0, pfA);                                                      \
    RD_FA(A0v, 1);                                                                     \
    SBAR0(); BARX();                                                                   \
    /* q1 */                                                                           \
    LGKM0();                                                                           \
    MMA_Q(1);                                                                          \
    if (PF) STAGE_A(A2v, 1, pfA);                                                      \
    RD_FA(A0v, 2);                                                                     \
    SBAR0(); BARX();                                                                   \
    /* q2 */                                                                           \
    LGKM0();                                                                           \
    MMA_Q(2);                                                                          \
    if (PF) {                                                                          \
      STAGE_B(BSv, 0, pfB);                                                            \
      asm volatile("s_waitcnt vmcnt(6)" ::: "memory");                                 \
    } else if (NX) {                                                                   \
      asm volatile("s_waitcnt vmcnt(0)" ::: "memory");                                 \
    }                                                                                  \
    RD_FA(A0v, 3);                                                                     \
    SBAR0(); BARX();                                                                   \
    /* q3 */                                                                           \
    LGKM0();                                                                           \
    MMA_Q(3);                                                                          \
    if (PF) STAGE_B(BSv, 1, pfB);                                                      \
    if (NX) {                                                                          \
      RD_FB(BTv);                                                                      \
      RD_FA(A1v, 0);                                                                   \
      SBAR0(); BARX();                                                                 \
    }                                                                                  \
    if (PF) { pfA += 64; pfB += 64; }                                                  \
  } while (0)

  // prologue: stage A(0)->As0, B(0)->Bs0, A(1)->As1, B(1)->Bs1 (16 loads);
  // drain the 8 oldest (tile 0); pre-read tile 0 fragments.
  STAGE_A(0, 0, Abl); STAGE_A(0, 1, Abl);
  STAGE_B(0, 0, Bbl); STAGE_B(0, 1, Bbl);
  STAGE_A(1, 0, Abl + 64); STAGE_A(1, 1, Abl + 64);
  STAGE_B(1, 0, Bbl + 64); STAGE_B(1, 1, Bbl + 64);
  asm volatile("s_waitcnt vmcnt(8)" ::: "memory");
  BARX();
  RD_FB(0);
  RD_FA(0, 0);

  const int NT = K >> 6;          // 16 or 64; both == 4 (mod 6), >= 10
  const int nch = (NT - 4) / 6;
  const bf16* pfA = Abl + 2 * 64;
  const bf16* pfB = Bbl + 2 * 64;
#pragma unroll 1
  for (int ch = 0; ch < nch; ++ch) {
    TILE3(0, 1, 2, 0, 1, true, true);
    TILE3(1, 2, 0, 1, 0, true, true);
    TILE3(2, 0, 1, 0, 1, true, true);
    TILE3(0, 1, 2, 1, 0, true, true);
    TILE3(1, 2, 0, 0, 1, true, true);
    TILE3(2, 0, 1, 1, 0, true, true);
  }
  // tail 4 tiles: t = NT-4 .. NT-1 (NT-4 == 0 mod 6 -> pattern restarts)
  TILE3(0, 1, 2, 0, 1, true, true);
  TILE3(1, 2, 0, 1, 0, true, true);
  TILE3(2, 0, 1, 0, 1, false, true);
  TILE3(0, 1, 2, 1, 0, false, false);

#undef BARX
#undef SBAR0
#undef STAGE_A
#undef STAGE_B
#undef RD_FA
#undef RD_FB
#undef MMA_Q
#undef LGKM0
#undef TILE3

  // epilogue: n innermost -> four adjacent 64B chunks per (m,r2)
  const int lc = l & 15;
  const int lr = (l >> 4) * 4;
#pragma unroll
  for (int m = 0; m < 8; ++m) {
    const int row = bm * 256 + wr * 128 + m * 16 + lr;
#pragma unroll
    for (int r2 = 0; r2 < 4; ++r2) {
      const size_t rowoff = (size_t)(row + r2) * N;
#pragma unroll
      for (int n = 0; n < 4; ++n) {
        const int col = bn * 256 + wc * 64 + n * 16 + lc;
        float v = acc[m][n][r2] + bias[col];
        const size_t off = rowoff + col;
        if constexpr (EPI == 1) v = v / (1.f + __expf(-v));
        if constexpr (EPI == 2) {
          ((float*)C)[off] = res[off] + v;
        } else {
          ((bf16*)C)[off] = f2bf(v);
        }
      }
    }
  }
  (void)M;
}

// ---- per-head k/th matmuls + gate math -> a,b ; FUSED per-chunk segment scan -------
__global__ __launch_bounds__(256)
void heads_kernel(const bf16* __restrict__ piB,
                  const float* __restrict__ wz, const float* __restrict__ bz,
                  const float* __restrict__ wh, const float* __restrict__ bh,
                  bf16* __restrict__ aB, bf16* __restrict__ bB,
                  float* __restrict__ cA, float* __restrict__ cB) {
  __shared__ float wzs[4096], whs[4096];
  __shared__ float pisT[64 * 68];
  __shared__ float segA[4][64], segB[4][64];
  const int h = blockIdx.y;
  const int t0 = blockIdx.x * 64;  // global row (n*L + t)
  const int tid = threadIdx.x;
#pragma unroll
  for (int i = tid; i < 4096; i += 256) {
    wzs[i] = wz[i];
    whs[i] = wh[i];
  }
#pragma unroll
  for (int rr = 0; rr < 4; ++rr) {  // vectorized pi staging (short4), transposed store
    const int v = tid + rr * 256;   // 1024 short4 groups
    const int row = v >> 4, c4 = (v & 15) * 4;
    short4v p4 = *(const short4v*)(piB + (size_t)(t0 + row) * 1024 + h * 64 + c4);
    pisT[(c4 + 0) * 68 + row] = s2f(p4[0]);
    pisT[(c4 + 1) * 68 + row] = s2f(p4[1]);
    pisT[(c4 + 2) * 68 + row] = s2f(p4[2]);
    pisT[(c4 + 3) * 68 + row] = s2f(p4[3]);
  }
  __syncthreads();
  const int hd = tid & 63;
  const int tb = (tid >> 6) * 16;
  float accK[16], accT[16];
  const float bzv = bz[hd], bhv = bh[hd];
#pragma unroll
  for (int i = 0; i < 16; ++i) { accK[i] = bzv; accT[i] = bhv; }
  for (int j = 0; j < 64; ++j) {
    const float wzv = wzs[j * 64 + hd];
    const float whv = whs[j * 64 + hd];
    const float4* pj = (const float4*)&pisT[j * 68 + tb];
    const float4 p0 = pj[0], p1 = pj[1], p2 = pj[2], p3 = pj[3];
    float p[16] = {p0.x, p0.y, p0.z, p0.w, p1.x, p1.y, p1.z, p1.w,
                   p2.x, p2.y, p2.z, p2.w, p3.x, p3.y, p3.z, p3.w};
#pragma unroll
    for (int i = 0; i < 16; ++i) {
      accK[i] = fmaf(p[i], wzv, accK[i]);
      accT[i] = fmaf(p[i], whv, accT[i]);
    }
  }
  float As = 1.f, Bs = 0.f;
#pragma unroll
  for (int i = 0; i < 16; ++i) {
    const float k = accK[i], th = accT[i];
    const float sig = 1.f / (1.f + __expf(-k));      // sigmoid(k)
    const float a = 1.f - sig;                        // exp(-softplus(k))
    const float gg = th >= 0.f ? th + 0.5f : 1.f / (1.f + __expf(-th));  // g(th)
    const float bb = sig * gg;                        // exp(log_z + log_th)
    Bs = fmaf(a, Bs, bb);                             // t ascending within thread
    As *= a;
    const size_t idx = (size_t)(t0 + tb + i) * 1024 + h * 64 + hd;
    aB[idx] = f2bf(a);
    bB[idx] = f2bf(bb);
  }
  segA[tid >> 6][hd] = As;
  segB[tid >> 6][hd] = Bs;
  __syncthreads();
  if (tid < 64) {
    float A = segA[0][tid], B = segB[0][tid];
#pragma unroll
    for (int s = 1; s < 4; ++s) {
      B = fmaf(segA[s][tid], B, segB[s][tid]);
      A *= segA[s][tid];
    }
    const int n = t0 >> 12;
    const int chunk = (t0 >> 6) & 63;
    const size_t o = ((size_t)(n * 64 + chunk)) * 1024 + h * 64 + tid;
    cA[o] = A;
    cB[o] = B;
  }
}

// ---------------- chunk-state scan ----------------
__global__ __launch_bounds__(256)
void scan_phase2(const float* __restrict__ h0,
                 const float* __restrict__ cA, const float* __restrict__ cB,
                 float* __restrict__ hst) {
  const int idx = blockIdx.x * 256 + threadIdx.x;  // 4096
  const int c = idx & 1023;
  const int n = idx >> 10;
  float hv = h0[(size_t)n * 1024 + c];
  hv = hv >= 0.f ? hv + 0.5f : 1.f / (1.f + __expf(-hv));  // g(h0)
  for (int ch = 0; ch < 64; ++ch) {
    const size_t o = ((size_t)(n * 64 + ch)) * 1024 + c;
    hst[o] = hv;
    hv = fmaf(cA[o], hv, cB[o]);
  }
}

// ---------------- final scan pass, 8 channels/thread (short8/float4 coalesced) ------
__global__ __launch_bounds__(128)
void scan_phase3(const bf16* __restrict__ aB, const bf16* __restrict__ bB,
                 const float* __restrict__ hst,
                 float* __restrict__ rnn, bf16* __restrict__ rnnB) {
  const int idx = blockIdx.x * 128 + threadIdx.x;  // 32768
  const int c8 = idx & 127;        // channel-group of 8
  const int chunk = (idx >> 7) & 63;
  const int n = idx >> 13;
  const int c0 = c8 * 8;
  float hv[8];
  const float4* hsrc = (const float4*)(hst + ((size_t)(n * 64 + chunk)) * 1024 + c0);
  float4 ha = hsrc[0], hb = hsrc[1];
  hv[0] = ha.x; hv[1] = ha.y; hv[2] = ha.z; hv[3] = ha.w;
  hv[4] = hb.x; hv[5] = hb.y; hv[6] = hb.z; hv[7] = hb.w;
  size_t base = ((size_t)(n * 4096 + chunk * 64)) * 1024 + c0;
#pragma unroll 4
  for (int s = 0; s < 64; ++s) {
    const short8 a8 = *(const short8*)(aB + base);
    const short8 b8 = *(const short8*)(bB + base);
    short8 ob;
    float4 o0, o1;
#pragma unroll
    for (int j = 0; j < 8; ++j) {
      hv[j] = fmaf(s2f(a8[j]), hv[j], s2f(b8[j]));
      ob[j] = f2s(hv[j]);
    }
    o0.x = hv[0]; o0.y = hv[1]; o0.z = hv[2]; o0.w = hv[3];
    o1.x = hv[4]; o1.y = hv[5]; o1.z = hv[6]; o1.w = hv[7];
    ((float4*)(rnn + base))[0] = o0;
    ((float4*)(rnn + base))[1] = o1;
    *(short8*)(rnnB + base) = ob;
    base += 1024;
  }
}

// ---------------- host ----------------
extern "C" void kernel_launch(void* const* d_in, const int* in_sizes, int n_in,
                              void* d_out, int out_size, void* d_ws, size_t ws_size,
                              hipStream_t stream) {
  const float* x    = (const float*)d_in[0];
  const float* h0   = (const float*)d_in[1];
  const float* w_in = (const float*)d_in[2];
  const float* b_in = (const float*)d_in[3];
  const float* wz   = (const float*)d_in[4];
  const float* bz   = (const float*)d_in[5];
  const float* wh   = (const float*)d_in[6];
  const float* bh   = (const float*)d_in[7];
  const float* w_out= (const float*)d_in[8];
  const float* b_out= (const float*)d_in[9];
  const float* ln1g = (const float*)d_in[10];
  const float* ln1b = (const float*)d_in[11];
  const float* ln2g = (const float*)d_in[12];
  const float* ln2b = (const float*)d_in[13];
  const float* mw1  = (const float*)d_in[14];
  const float* mb1  = (const float*)d_in[15];
  const float* mw2  = (const float*)d_in[16];
  const float* mb2  = (const float*)d_in[17];
  const float* mw3  = (const float*)d_in[18];
  const float* mb3  = (const float*)d_in[19];
  (void)in_sizes; (void)n_in; (void)out_size;

  float* out0 = (float*)d_out;                       // holds xr, then x+y (in place)
  float* out1 = (float*)d_out + (size_t)16384 * 1024;  // rnn_states

  char* ws = (char*)d_ws;
  size_t o = 0;
  auto take = [&](size_t bytes) { char* p = ws + o; o += (bytes + 255) & ~(size_t)255; return p; };
  bf16* w_inT = (bf16*)take((size_t)1024 * 1024 * 2);
  bf16* w_outT= (bf16*)take((size_t)1024 * 1024 * 2);
  bf16* mw1T  = (bf16*)take((size_t)4096 * 1024 * 2);
  bf16* mw2T  = (bf16*)take((size_t)4096 * 4096 * 2);
  bf16* mw3T  = (bf16*)take((size_t)4096 * 1024 * 2);
  bf16* lnxB  = (bf16*)take((size_t)16384 * 1024 * 2);  // reused: rnnB, ln2B
  bf16* piB   = (bf16*)take((size_t)16384 * 1024 * 2);
  bf16* aB    = (bf16*)take((size_t)16384 * 1024 * 2);  // reused: t1 (chunked path)
  bf16* bB    = (bf16*)take((size_t)16384 * 1024 * 2);  // reused: t2 (chunked path)
  float* cA   = (float*)take((size_t)4 * 64 * 1024 * 4);
  float* cB   = (float*)take((size_t)4 * 64 * 1024 * 4);
  float* hst  = (float*)take((size_t)4 * 64 * 1024 * 4);
  if (o > ws_size) return;  // workspace too small -> fail loudly via wrong output

  // adaptive: full-M MLP intermediates if workspace allows
  const size_t bigbuf = (size_t)16384 * 4096 * 2;  // 128 MiB each
  bf16* t1 = aB;
  bf16* t2 = bB;
  bool big = false;
  if (o + 2 * bigbuf <= ws_size) {
    big = true;
    t1 = (bf16*)take(bigbuf);
    t2 = (bf16*)take(bigbuf);
  }

  // all weights -> bf16 transposed, one launch
  wconv_all<<<26624, 256, 0, stream>>>(w_in, w_out, mw1, mw2, mw3,
                                       w_inT, w_outT, mw1T, mw2T, mw3T);

  // LN1 -> GEMM1 (pi)
  ln_kernel<<<16384, 256, 0, stream>>>(x, ln1g, ln1b, lnxB);
  gemm256<0><<<256, 512, 0, stream>>>(lnxB, w_inT, b_in, nullptr, piB, 16384, 1024, 1024);

  // per-head gates + fused chunk-scan -> a,b,cA,cB ; chunk-state scan ; final pass
  heads_kernel<<<dim3(256, 16), 256, 0, stream>>>(piB, wz, bz, wh, bh, aB, bB, cA, cB);
  scan_phase2<<<16, 256, 0, stream>>>(h0, cA, cB, hst);
  scan_phase3<<<256, 128, 0, stream>>>(aB, bB, hst, out1, lnxB /*rnnB*/);

  // xr = x + rnn @ w_out + b_out   (written to out0)
  gemm256<2><<<256, 512, 0, stream>>>(lnxB, w_outT, b_out, x, out0, 16384, 1024, 1024);

  // LN2 -> MLP, final GEMM adds xr in place in out0
  ln_kernel<<<16384, 256, 0, stream>>>(out0, ln2g, ln2b, lnxB /*ln2B*/);
  if (big) {
    gemm256<1><<<1024, 512, 0, stream>>>(lnxB, mw1T, mb1, nullptr, t1, 16384, 4096, 1024);
    gemm256<1><<<1024, 512, 0, stream>>>(t1, mw2T, mb2, nullptr, t2, 16384, 4096, 4096);
    // mw3 on the 256-tile path: grid (16384/256)x(1024/256) = 256 blocks = 1/CU,
    // halves A-panel re-reads vs gemm128@1024 blocks and amortizes the f32 epilogue
    gemm256<2><<<256, 512, 0, stream>>>(t2, mw3T, mb3, out0, out0, 16384, 1024, 4096);
  } else {
    for (int mc = 0; mc < 4; ++mc) {
      const bf16* a3 = lnxB + (size_t)mc * 4096 * 1024;
      gemm256<1><<<256, 512, 0, stream>>>(a3, mw1T, mb1, nullptr, t1, 4096, 4096, 1024);
      gemm256<1><<<256, 512, 0, stream>>>(t1, mw2T, mb2, nullptr, t2, 4096, 4096, 4096);
      float* oc = out0 + (size_t)mc * 4096 * 1024;
      gemm128<2><<<256, 256, 0, stream>>>(t2, mw3T, mb3, oc, oc, 4096, 1024, 4096);
    }
  }
}

// Round 12
// 1124.364 us; speedup vs baseline: 1.0470x; 1.0057x over previous
//
#include <hip/hip_runtime.h>
#include <hip/hip_bf16.h>

typedef __attribute__((ext_vector_type(8))) short short8;
typedef __attribute__((ext_vector_type(4))) short short4v;
typedef __attribute__((ext_vector_type(4))) float f32x4;
using bf16 = __hip_bfloat16;

#define DEV static __device__ __forceinline__

DEV float bf2f(bf16 v) { return __bfloat162float(v); }
DEV bf16 f2bf(float v) { return __float2bfloat16(v); }
DEV float s2f(short s) {
  union { unsigned u; float f; } v;
  v.u = ((unsigned)(unsigned short)s) << 16;
  return v.f;
}
DEV short f2s(float v) {
  bf16 b = __float2bfloat16(v);
  return *(short*)&b;
}

DEV void gld_lds16(const void* g, void* l) {
  __builtin_amdgcn_global_load_lds(
      (const __attribute__((address_space(1))) void*)g,
      (__attribute__((address_space(3))) void*)l, 16, 0, 0);
}

// ---- prep: all weight convert+transpose AND LN1, one launch (all pure-BW work) ----
// blocks [0, 26624): wconv (w_in, w_out, mw1, mw2, mw3); blocks [26624, 43008): LN1.
// Branches are block-uniform; merging overlaps the independent memory streams.
__global__ __launch_bounds__(256)
void prep_kernel(const float* __restrict__ w_in, const float* __restrict__ w_out,
                 const float* __restrict__ mw1, const float* __restrict__ mw2,
                 const float* __restrict__ mw3,
                 bf16* __restrict__ w_inT, bf16* __restrict__ w_outT,
                 bf16* __restrict__ mw1T, bf16* __restrict__ mw2T,
                 bf16* __restrict__ mw3T,
                 const float* __restrict__ x, const float* __restrict__ ln1g,
                 const float* __restrict__ ln1b, bf16* __restrict__ lnx) {
  __shared__ float tile[32][33];
  __shared__ float red[8];
  const int b = blockIdx.x;
  if (b >= 26624) {
    // ---- LN1 branch (D=1024), f32 in -> bf16 out ----
    const int row = b - 26624;
    const int t = threadIdx.x;
    const float4 v = ((const float4*)(x + (size_t)row * 1024))[t];
    float s = v.x + v.y + v.z + v.w;
    float ss = v.x * v.x + v.y * v.y + v.z * v.z + v.w * v.w;
#pragma unroll
    for (int off = 32; off > 0; off >>= 1) {
      s += __shfl_down(s, off);
      ss += __shfl_down(ss, off);
    }
    if ((t & 63) == 0) { red[(t >> 6) * 2] = s; red[(t >> 6) * 2 + 1] = ss; }
    __syncthreads();
    s = red[0] + red[2] + red[4] + red[6];
    ss = red[1] + red[3] + red[5] + red[7];
    const float mu = s * (1.f / 1024.f);
    const float rstd = rsqrtf(ss * (1.f / 1024.f) - mu * mu + 1e-5f);
    const float4 g4 = ((const float4*)ln1g)[t];
    const float4 b4 = ((const float4*)ln1b)[t];
    struct alignas(8) B4 { bf16 v[4]; } o;
    o.v[0] = f2bf((v.x - mu) * rstd * g4.x + b4.x);
    o.v[1] = f2bf((v.y - mu) * rstd * g4.y + b4.y);
    o.v[2] = f2bf((v.z - mu) * rstd * g4.z + b4.z);
    o.v[3] = f2bf((v.w - mu) * rstd * g4.w + b4.w);
    *(B4*)(lnx + (size_t)row * 1024 + t * 4) = o;
    return;
  }
  // ---- wconv branch: (K,N) f32 -> (N,K) bf16 ----
  const float* w;
  bf16* wT;
  int K, N, tb, kshift;
  if (b < 1024)       { w = w_in;  wT = w_inT;  K = 1024; N = 1024; tb = b;         kshift = 5; }
  else if (b < 2048)  { w = w_out; wT = w_outT; K = 1024; N = 1024; tb = b - 1024;  kshift = 5; }
  else if (b < 6144)  { w = mw1;   wT = mw1T;   K = 1024; N = 4096; tb = b - 2048;  kshift = 5; }
  else if (b < 22528) { w = mw2;   wT = mw2T;   K = 4096; N = 4096; tb = b - 6144;  kshift = 7; }
  else                { w = mw3;   wT = mw3T;   K = 4096; N = 1024; tb = b - 22528; kshift = 7; }
  const int kt = (tb & ((1 << kshift) - 1)) * 32;
  const int nt = (tb >> kshift) * 32;
  const int tx = threadIdx.x & 31, ty = threadIdx.x >> 5;  // ty 0..7
#pragma unroll
  for (int i = 0; i < 32; i += 8)
    tile[ty + i][tx] = w[(size_t)(kt + ty + i) * N + nt + tx];
  __syncthreads();
#pragma unroll
  for (int i = 0; i < 32; i += 8)
    wT[(size_t)(nt + ty + i) * K + kt + tx] = f2bf(tile[tx][ty + i]);
}

// ---------------- LayerNorm (D=1024), f32 in -> bf16 out (used for LN2) ------------
__global__ __launch_bounds__(256)
void ln_kernel(const float* __restrict__ x, const float* __restrict__ g,
               const float* __restrict__ b, bf16* __restrict__ out) {
  const int row = blockIdx.x;
  const int t = threadIdx.x;
  const float4 v = ((const float4*)(x + (size_t)row * 1024))[t];
  float s = v.x + v.y + v.z + v.w;
  float ss = v.x * v.x + v.y * v.y + v.z * v.z + v.w * v.w;
#pragma unroll
  for (int off = 32; off > 0; off >>= 1) {
    s += __shfl_down(s, off);
    ss += __shfl_down(ss, off);
  }
  __shared__ float red[8];
  if ((t & 63) == 0) { red[(t >> 6) * 2] = s; red[(t >> 6) * 2 + 1] = ss; }
  __syncthreads();
  s = red[0] + red[2] + red[4] + red[6];
  ss = red[1] + red[3] + red[5] + red[7];
  const float mu = s * (1.f / 1024.f);
  const float rstd = rsqrtf(ss * (1.f / 1024.f) - mu * mu + 1e-5f);
  const float4 g4 = ((const float4*)g)[t];
  const float4 b4 = ((const float4*)b)[t];
  struct alignas(8) B4 { bf16 v[4]; } o;
  o.v[0] = f2bf((v.x - mu) * rstd * g4.x + b4.x);
  o.v[1] = f2bf((v.y - mu) * rstd * g4.y + b4.y);
  o.v[2] = f2bf((v.z - mu) * rstd * g4.z + b4.z);
  o.v[3] = f2bf((v.w - mu) * rstd * g4.w + b4.w);
  *(B4*)(out + (size_t)row * 1024 + t * 4) = o;
}

// ---------------- m97-style 128x128 bf16 MFMA GEMM, NT (A:MxK, BT:NxK) ----------------
// kept only for the small-workspace fallback path
template <int EPI>
__global__ __launch_bounds__(256, 2)
void gemm128(const bf16* __restrict__ A, const bf16* __restrict__ BT,
             const float* __restrict__ bias, const float* __restrict__ res,
             void* __restrict__ C, int M, int N, int K) {
  __shared__ short As[128 * 64];
  __shared__ short Bs[128 * 64];
  const int tid = threadIdx.x;
  const int l = tid & 63;
  const int w = tid >> 6;
  const int wr = w >> 1, wc = w & 1;

  const int nbn = N >> 7;
  const int nwg = gridDim.x;
  const int bid = blockIdx.x;
  const int q = nwg >> 3, r = nwg & 7;
  const int xcd = bid & 7, lin = bid >> 3;
  const int wg = (xcd < r ? xcd * (q + 1) : r * (q + 1) + (xcd - r) * q) + lin;
  const int bm = wg / nbn, bn = wg % nbn;

  const bf16* Ab = A + (size_t)bm * 128 * K;
  const bf16* Bb = BT + (size_t)bn * 128 * K;

  f32x4 acc[4][4];
#pragma unroll
  for (int i = 0; i < 4; ++i)
#pragma unroll
    for (int j = 0; j < 4; ++j) acc[i][j] = (f32x4){0.f, 0.f, 0.f, 0.f};

  const int srow = l >> 3;
  const int scol = (((l & 7) ^ (l >> 3)) << 3);

  for (int k0 = 0; k0 < K; k0 += 64) {
    __syncthreads();
#pragma unroll
    for (int p = 0; p < 4; ++p) {
      const int rowA = p * 32 + w * 8 + srow;
      gld_lds16(Ab + (size_t)rowA * K + k0 + scol, As + (p * 32 + w * 8) * 64);
      gld_lds16(Bb + (size_t)rowA * K + k0 + scol, Bs + (p * 32 + w * 8) * 64);
    }
    __syncthreads();
    const int xr = (l & 7) << 3;
#pragma unroll
    for (int kk = 0; kk < 2; ++kk) {
      short8 fa[4], fb[4];
#pragma unroll
      for (int m = 0; m < 4; ++m)
        fa[m] = *(const short8*)&As[(wr * 64 + m * 16 + (l & 15)) * 64 +
                                    ((kk * 32 + (l >> 4) * 8) ^ xr)];
#pragma unroll
      for (int n = 0; n < 4; ++n)
        fb[n] = *(const short8*)&Bs[(wc * 64 + n * 16 + (l & 15)) * 64 +
                                    ((kk * 32 + (l >> 4) * 8) ^ xr)];
#pragma unroll
      for (int m = 0; m < 4; ++m)
#pragma unroll
        for (int n = 0; n < 4; ++n)
          acc[m][n] = __builtin_amdgcn_mfma_f32_16x16x32_bf16(fa[m], fb[n], acc[m][n], 0, 0, 0);
    }
  }

  // epilogue: n innermost so the four 64B lane-chunks per (m,r2) are adjacent bursts
  const int lc = l & 15;
  const int lr = (l >> 4) * 4;
#pragma unroll
  for (int m = 0; m < 4; ++m) {
    const int row = bm * 128 + wr * 64 + m * 16 + lr;
#pragma unroll
    for (int r2 = 0; r2 < 4; ++r2) {
      const size_t rowoff = (size_t)(row + r2) * N;
#pragma unroll
      for (int n = 0; n < 4; ++n) {
        const int col = bn * 128 + wc * 64 + n * 16 + lc;
        float v = acc[m][n][r2] + bias[col];
        const size_t off = rowoff + col;
        if constexpr (EPI == 1) v = v / (1.f + __expf(-v));
        if constexpr (EPI == 2) {
          ((float*)C)[off] = res[off] + v;
        } else {
          ((bf16*)C)[off] = f2bf(v);
        }
      }
    }
  }
  (void)M;
}

// ------- 256x256 bf16 MFMA GEMM, A-triple-buffered deep pipeline (r8 best) ----------
// 512 threads = 8 waves (2M x 4N); per-wave 128x64 (acc[8][4]); single fragment set.
// LDS = 3x32KB A + 2x32KB B = 160 KiB. Buffer indices compile-time (6-periodic).
// Best-measured gemm256 variant (r8/r10/r11: mw2 ~554us, MfmaUtil ~42.6).
// NOTE (session record): six schedule variants (8-phase, reg-dbuf, sched-pins,
// tail-read, triple-buf-A, k-half stagger) all measure 41-44% MfmaUtil at this
// shape; this is the plateau of blind source-level scheduling on this structure.
template <int EPI>
__global__ __launch_bounds__(512, 2)
void gemm256(const bf16* __restrict__ A, const bf16* __restrict__ BT,
             const float* __restrict__ bias, const float* __restrict__ res,
             void* __restrict__ C, int M, int N, int K) {
  __shared__ alignas(16) short As[3][256 * 64];
  __shared__ alignas(16) short Bs[2][256 * 64];
  const int tid = threadIdx.x;
  const int l = tid & 63;
  const int w = tid >> 6;   // 0..7
  const int wr = w >> 2;    // 0..1 (M half)
  const int wc = w & 3;     // 0..3 (N quarter)

  const int nbn = N >> 8;
  const int nwg = gridDim.x;
  const int bid = blockIdx.x;
  const int q = nwg >> 3, r = nwg & 7;
  const int xcd = bid & 7, lin = bid >> 3;
  const int wg = (xcd < r ? xcd * (q + 1) : r * (q + 1) + (xcd - r) * q) + lin;
  const int bm = wg / nbn, bn = wg % nbn;

  const bf16* Ab = A + (size_t)bm * 256 * K;
  const bf16* Bb = BT + (size_t)bn * 256 * K;

  const int gcol = ((l & 7) ^ (l >> 3)) << 3;  // pre-swizzled source col (shorts)
  const int fr = l & 15;
  const int kq = (l >> 4) << 3;
  const int xr = (l & 7) << 3;
  const int k0s = kq ^ xr;
  const int k1s = (32 + kq) ^ xr;

  const bf16* Abl = Ab + (size_t)(w * 16 + (l >> 3)) * K + gcol;
  const bf16* Bbl = Bb + (size_t)(w * 16 + (l >> 3)) * K + gcol;

  f32x4 acc[8][4];
#pragma unroll
  for (int i = 0; i < 8; ++i)
#pragma unroll
    for (int j = 0; j < 4; ++j) acc[i][j] = (f32x4){0.f, 0.f, 0.f, 0.f};

  short8 fa[2][2];   // [m-pair][khalf]
  short8 fb[4][2];   // [n][khalf]

#define BARX() __builtin_amdgcn_s_barrier()
#define SBAR0() __builtin_amdgcn_sched_barrier(0)

#define STAGE_A(BUF, HALF, P)                                                      \
  do {                                                                             \
    gld_lds16((P) + (size_t)((HALF) * 128) * K,                                    \
              &As[BUF][((HALF) * 128 + w * 16) * 64]);                             \
    gld_lds16((P) + (size_t)((HALF) * 128 + 8) * K,                                \
              &As[BUF][((HALF) * 128 + w * 16 + 8) * 64]);                         \
  } while (0)

#define STAGE_B(BUF, HALF, P)                                                      \
  do {                                                                             \
    gld_lds16((P) + (size_t)((HALF) * 128) * K,                                    \
              &Bs[BUF][((HALF) * 128 + w * 16) * 64]);                             \
    gld_lds16((P) + (size_t)((HALF) * 128 + 8) * K,                                \
              &Bs[BUF][((HALF) * 128 + w * 16 + 8) * 64]);                         \
  } while (0)

#define RD_FA(BUF, Q)                                                                    \
  do {                                                                                  \
    fa[0][0] = *(const short8*)&As[BUF][(wr * 128 + (Q) * 32 + fr) * 64 + k0s];         \
    fa[0][1] = *(const short8*)&As[BUF][(wr * 128 + (Q) * 32 + fr) * 64 + k1s];         \
    fa[1][0] = *(const short8*)&As[BUF][(wr * 128 + (Q) * 32 + 16 + fr) * 64 + k0s];    \
    fa[1][1] = *(const short8*)&As[BUF][(wr * 128 + (Q) * 32 + 16 + fr) * 64 + k1s];    \
  } while (0)

#define RD_FB(BUF)                                                                      \
  do {                                                                                 \
    _Pragma("unroll") for (int n_ = 0; n_ < 4; ++n_) {                                 \
      fb[n_][0] = *(const short8*)&Bs[BUF][(wc * 64 + n_ * 16 + fr) * 64 + k0s];       \
      fb[n_][1] = *(const short8*)&Bs[BUF][(wc * 64 + n_ * 16 + fr) * 64 + k1s];       \
    }                                                                                  \
  } while (0)

#define MMA_Q(Q)                                                                        \
  do {                                                                                 \
    __builtin_amdgcn_s_setprio(1);                                                     \
    _Pragma("unroll") for (int n_ = 0; n_ < 4; ++n_) {                                 \
      acc[2 * (Q)][n_] = __builtin_amdgcn_mfma_f32_16x16x32_bf16(                      \
          fa[0][0], fb[n_][0], acc[2 * (Q)][n_], 0, 0, 0);                             \
      acc[2 * (Q) + 1][n_] = __builtin_amdgcn_mfma_f32_16x16x32_bf16(                  \
          fa[1][0], fb[n_][0], acc[2 * (Q) + 1][n_], 0, 0, 0);                         \
    }                                                                                  \
    _Pragma("unroll") for (int n_ = 0; n_ < 4; ++n_) {                                 \
      acc[2 * (Q)][n_] = __builtin_amdgcn_mfma_f32_16x16x32_bf16(                      \
          fa[0][1], fb[n_][1], acc[2 * (Q)][n_], 0, 0, 0);                             \
      acc[2 * (Q) + 1][n_] = __builtin_amdgcn_mfma_f32_16x16x32_bf16(                  \
          fa[1][1], fb[n_][1], acc[2 * (Q) + 1][n_], 0, 0, 0);                         \
    }                                                                                  \
    __builtin_amdgcn_s_setprio(0);                                                     \
  } while (0)

#define LGKM0() do { asm volatile("s_waitcnt lgkmcnt(0)"); SBAR0(); } while (0)

#define TILE3(A0v, A1v, A2v, BSv, BTv, PF, NX)                                         \
  do {                                                                                 \
    /* q0 */                                                                           \
    LGKM0();                                                                           \
    MMA_Q(0);                                                                          \
    if (PF) STAGE_A(A2v, 0, pfA);                                                      \
    RD_FA(A0v, 1);                                                                     \
    SBAR0(); BARX();                                                                   \
    /* q1 */                                                                           \
    LGKM0();                                                                           \
    MMA_Q(1);                                                                          \
    if (PF) STAGE_A(A2v, 1, pfA);                                                      \
    RD_FA(A0v, 2);                                                                     \
    SBAR0(); BARX();                                                                   \
    /* q2 */                                                                           \
    LGKM0();                                                                           \
    MMA_Q(2);                                                                          \
    if (PF) {                                                                          \
      STAGE_B(BSv, 0, pfB);                                                            \
      asm volatile("s_waitcnt vmcnt(6)" ::: "memory");                                 \
    } else if (NX) {                                                                   \
      asm volatile("s_waitcnt vmcnt(0)" ::: "memory");                                 \
    }                                                                                  \
    RD_FA(A0v, 3);                                                                     \
    SBAR0(); BARX();                                                                   \
    /* q3 */                                                                           \
    LGKM0();                                                                           \
    MMA_Q(3);                                                                          \
    if (PF) STAGE_B(BSv, 1, pfB);                                                      \
    if (NX) {                                                                          \
      RD_FB(BTv);                                                                      \
      RD_FA(A1v, 0);                                                                   \
      SBAR0(); BARX();                                                                 \
    }                                                                                  \
    if (PF) { pfA += 64; pfB += 64; }                                                  \
  } while (0)

  // prologue: stage A(0)->As0, B(0)->Bs0, A(1)->As1, B(1)->Bs1 (16 loads);
  // drain the 8 oldest (tile 0); pre-read tile 0 fragments.
  STAGE_A(0, 0, Abl); STAGE_A(0, 1, Abl);
  STAGE_B(0, 0, Bbl); STAGE_B(0, 1, Bbl);
  STAGE_A(1, 0, Abl + 64); STAGE_A(1, 1, Abl + 64);
  STAGE_B(1, 0, Bbl + 64); STAGE_B(1, 1, Bbl + 64);
  asm volatile("s_waitcnt vmcnt(8)" ::: "memory");
  BARX();
  RD_FB(0);
  RD_FA(0, 0);

  const int NT = K >> 6;          // 16 or 64; both == 4 (mod 6), >= 10
  const int nch = (NT - 4) / 6;
  const bf16* pfA = Abl + 2 * 64;
  const bf16* pfB = Bbl + 2 * 64;
#pragma unroll 1
  for (int ch = 0; ch < nch; ++ch) {
    TILE3(0, 1, 2, 0, 1, true, true);
    TILE3(1, 2, 0, 1, 0, true, true);
    TILE3(2, 0, 1, 0, 1, true, true);
    TILE3(0, 1, 2, 1, 0, true, true);
    TILE3(1, 2, 0, 0, 1, true, true);
    TILE3(2, 0, 1, 1, 0, true, true);
  }
  // tail 4 tiles: t = NT-4 .. NT-1 (NT-4 == 0 mod 6 -> pattern restarts)
  TILE3(0, 1, 2, 0, 1, true, true);
  TILE3(1, 2, 0, 1, 0, true, true);
  TILE3(2, 0, 1, 0, 1, false, true);
  TILE3(0, 1, 2, 1, 0, false, false);

#undef BARX
#undef SBAR0
#undef STAGE_A
#undef STAGE_B
#undef RD_FA
#undef RD_FB
#undef MMA_Q
#undef LGKM0
#undef TILE3

  // epilogue: n innermost -> four adjacent 64B chunks per (m,r2)
  const int lc = l & 15;
  const int lr = (l >> 4) * 4;
#pragma unroll
  for (int m = 0; m < 8; ++m) {
    const int row = bm * 256 + wr * 128 + m * 16 + lr;
#pragma unroll
    for (int r2 = 0; r2 < 4; ++r2) {
      const size_t rowoff = (size_t)(row + r2) * N;
#pragma unroll
      for (int n = 0; n < 4; ++n) {
        const int col = bn * 256 + wc * 64 + n * 16 + lc;
        float v = acc[m][n][r2] + bias[col];
        const size_t off = rowoff + col;
        if constexpr (EPI == 1) v = v / (1.f + __expf(-v));
        if constexpr (EPI == 2) {
          ((float*)C)[off] = res[off] + v;
        } else {
          ((bf16*)C)[off] = f2bf(v);
        }
      }
    }
  }
  (void)M;
}

// ---- per-head k/th matmuls + gate math -> a,b ; FUSED per-chunk segment scan -------
__global__ __launch_bounds__(256)
void heads_kernel(const bf16* __restrict__ piB,
                  const float* __restrict__ wz, const float* __restrict__ bz,
                  const float* __restrict__ wh, const float* __restrict__ bh,
                  bf16* __restrict__ aB, bf16* __restrict__ bB,
                  float* __restrict__ cA, float* __restrict__ cB) {
  __shared__ float wzs[4096], whs[4096];
  __shared__ float pisT[64 * 68];
  __shared__ float segA[4][64], segB[4][64];
  const int h = blockIdx.y;
  const int t0 = blockIdx.x * 64;  // global row (n*L + t)
  const int tid = threadIdx.x;
#pragma unroll
  for (int i = tid; i < 4096; i += 256) {
    wzs[i] = wz[i];
    whs[i] = wh[i];
  }
#pragma unroll
  for (int rr = 0; rr < 4; ++rr) {  // vectorized pi staging (short4), transposed store
    const int v = tid + rr * 256;   // 1024 short4 groups
    const int row = v >> 4, c4 = (v & 15) * 4;
    short4v p4 = *(const short4v*)(piB + (size_t)(t0 + row) * 1024 + h * 64 + c4);
    pisT[(c4 + 0) * 68 + row] = s2f(p4[0]);
    pisT[(c4 + 1) * 68 + row] = s2f(p4[1]);
    pisT[(c4 + 2) * 68 + row] = s2f(p4[2]);
    pisT[(c4 + 3) * 68 + row] = s2f(p4[3]);
  }
  __syncthreads();
  const int hd = tid & 63;
  const int tb = (tid >> 6) * 16;
  float accK[16], accT[16];
  const float bzv = bz[hd], bhv = bh[hd];
#pragma unroll
  for (int i = 0; i < 16; ++i) { accK[i] = bzv; accT[i] = bhv; }
  for (int j = 0; j < 64; ++j) {
    const float wzv = wzs[j * 64 + hd];
    const float whv = whs[j * 64 + hd];
    const float4* pj = (const float4*)&pisT[j * 68 + tb];
    const float4 p0 = pj[0], p1 = pj[1], p2 = pj[2], p3 = pj[3];
    float p[16] = {p0.x, p0.y, p0.z, p0.w, p1.x, p1.y, p1.z, p1.w,
                   p2.x, p2.y, p2.z, p2.w, p3.x, p3.y, p3.z, p3.w};
#pragma unroll
    for (int i = 0; i < 16; ++i) {
      accK[i] = fmaf(p[i], wzv, accK[i]);
      accT[i] = fmaf(p[i], whv, accT[i]);
    }
  }
  float As = 1.f, Bs = 0.f;
#pragma unroll
  for (int i = 0; i < 16; ++i) {
    const float k = accK[i], th = accT[i];
    const float sig = 1.f / (1.f + __expf(-k));      // sigmoid(k)
    const float a = 1.f - sig;                        // exp(-softplus(k))
    const float gg = th >= 0.f ? th + 0.5f : 1.f / (1.f + __expf(-th));  // g(th)
    const float bb = sig * gg;                        // exp(log_z + log_th)
    Bs = fmaf(a, Bs, bb);                             // t ascending within thread
    As *= a;
    const size_t idx = (size_t)(t0 + tb + i) * 1024 + h * 64 + hd;
    aB[idx] = f2bf(a);
    bB[idx] = f2bf(bb);
  }
  segA[tid >> 6][hd] = As;
  segB[tid >> 6][hd] = Bs;
  __syncthreads();
  if (tid < 64) {
    float A = segA[0][tid], B = segB[0][tid];
#pragma unroll
    for (int s = 1; s < 4; ++s) {
      B = fmaf(segA[s][tid], B, segB[s][tid]);
      A *= segA[s][tid];
    }
    const int n = t0 >> 12;
    const int chunk = (t0 >> 6) & 63;
    const size_t o = ((size_t)(n * 64 + chunk)) * 1024 + h * 64 + tid;
    cA[o] = A;
    cB[o] = B;
  }
}

// ---------------- chunk-state scan (batched loads: 8 chunk-pairs per group) ---------
__global__ __launch_bounds__(256)
void scan_phase2(const float* __restrict__ h0,
                 const float* __restrict__ cA, const float* __restrict__ cB,
                 float* __restrict__ hst) {
  const int idx = blockIdx.x * 256 + threadIdx.x;  // 4096
  const int c = idx & 1023;
  const int n = idx >> 10;
  float hv = h0[(size_t)n * 1024 + c];
  hv = hv >= 0.f ? hv + 0.5f : 1.f / (1.f + __expf(-hv));  // g(h0)
  size_t o = ((size_t)(n * 64)) * 1024 + c;
  for (int g = 0; g < 8; ++g) {
    float av[8], bv[8];
#pragma unroll
    for (int s = 0; s < 8; ++s) {
      av[s] = cA[o + (size_t)s * 1024];
      bv[s] = cB[o + (size_t)s * 1024];
    }
#pragma unroll
    for (int s = 0; s < 8; ++s) {
      hst[o + (size_t)s * 1024] = hv;          // state BEFORE applying chunk s
      hv = fmaf(av[s], hv, bv[s]);
    }
    o += (size_t)8 * 1024;
  }
}

// ---------------- final scan pass, 8 channels/thread (short8/float4 coalesced) ------
__global__ __launch_bounds__(128)
void scan_phase3(const bf16* __restrict__ aB, const bf16* __restrict__ bB,
                 const float* __restrict__ hst,
                 float* __restrict__ rnn, bf16* __restrict__ rnnB) {
  const int idx = blockIdx.x * 128 + threadIdx.x;  // 32768
  const int c8 = idx & 127;        // channel-group of 8
  const int chunk = (idx >> 7) & 63;
  const int n = idx >> 13;
  const int c0 = c8 * 8;
  float hv[8];
  const float4* hsrc = (const float4*)(hst + ((size_t)(n * 64 + chunk)) * 1024 + c0);
  float4 ha = hsrc[0], hb = hsrc[1];
  hv[0] = ha.x; hv[1] = ha.y; hv[2] = ha.z; hv[3] = ha.w;
  hv[4] = hb.x; hv[5] = hb.y; hv[6] = hb.z; hv[7] = hb.w;
  size_t base = ((size_t)(n * 4096 + chunk * 64)) * 1024 + c0;
#pragma unroll 4
  for (int s = 0; s < 64; ++s) {
    const short8 a8 = *(const short8*)(aB + base);
    const short8 b8 = *(const short8*)(bB + base);
    short8 ob;
    float4 o0, o1;
#pragma unroll
    for (int j = 0; j < 8; ++j) {
      hv[j] = fmaf(s2f(a8[j]), hv[j], s2f(b8[j]));
      ob[j] = f2s(hv[j]);
    }
    o0.x = hv[0]; o0.y = hv[1]; o0.z = hv[2]; o0.w = hv[3];
    o1.x = hv[4]; o1.y = hv[5]; o1.z = hv[6]; o1.w = hv[7];
    ((float4*)(rnn + base))[0] = o0;
    ((float4*)(rnn + base))[1] = o1;
    *(short8*)(rnnB + base) = ob;
    base += 1024;
  }
}

// ---------------- host ----------------
extern "C" void kernel_launch(void* const* d_in, const int* in_sizes, int n_in,
                              void* d_out, int out_size, void* d_ws, size_t ws_size,
                              hipStream_t stream) {
  const float* x    = (const float*)d_in[0];
  const float* h0   = (const float*)d_in[1];
  const float* w_in = (const float*)d_in[2];
  const float* b_in = (const float*)d_in[3];
  const float* wz   = (const float*)d_in[4];
  const float* bz   = (const float*)d_in[5];
  const float* wh   = (const float*)d_in[6];
  const float* bh   = (const float*)d_in[7];
  const float* w_out= (const float*)d_in[8];
  const float* b_out= (const float*)d_in[9];
  const float* ln1g = (const float*)d_in[10];
  const float* ln1b = (const float*)d_in[11];
  const float* ln2g = (const float*)d_in[12];
  const float* ln2b = (const float*)d_in[13];
  const float* mw1  = (const float*)d_in[14];
  const float* mb1  = (const float*)d_in[15];
  const float* mw2  = (const float*)d_in[16];
  const float* mb2  = (const float*)d_in[17];
  const float* mw3  = (const float*)d_in[18];
  const float* mb3  = (const float*)d_in[19];
  (void)in_sizes; (void)n_in; (void)out_size;

  float* out0 = (float*)d_out;                       // holds xr, then x+y (in place)
  float* out1 = (float*)d_out + (size_t)16384 * 1024;  // rnn_states

  char* ws = (char*)d_ws;
  size_t o = 0;
  auto take = [&](size_t bytes) { char* p = ws + o; o += (bytes + 255) & ~(size_t)255; return p; };
  bf16* w_inT = (bf16*)take((size_t)1024 * 1024 * 2);
  bf16* w_outT= (bf16*)take((size_t)1024 * 1024 * 2);
  bf16* mw1T  = (bf16*)take((size_t)4096 * 1024 * 2);
  bf16* mw2T  = (bf16*)take((size_t)4096 * 4096 * 2);
  bf16* mw3T  = (bf16*)take((size_t)4096 * 1024 * 2);
  bf16* lnxB  = (bf16*)take((size_t)16384 * 1024 * 2);  // reused: rnnB, ln2B
  bf16* piB   = (bf16*)take((size_t)16384 * 1024 * 2);
  bf16* aB    = (bf16*)take((size_t)16384 * 1024 * 2);  // reused: t1 (chunked path)
  bf16* bB    = (bf16*)take((size_t)16384 * 1024 * 2);  // reused: t2 (chunked path)
  float* cA   = (float*)take((size_t)4 * 64 * 1024 * 4);
  float* cB   = (float*)take((size_t)4 * 64 * 1024 * 4);
  float* hst  = (float*)take((size_t)4 * 64 * 1024 * 4);
  if (o > ws_size) return;  // workspace too small -> fail loudly via wrong output

  // adaptive: full-M MLP intermediates if workspace allows
  const size_t bigbuf = (size_t)16384 * 4096 * 2;  // 128 MiB each
  bf16* t1 = aB;
  bf16* t2 = bB;
  bool big = false;
  if (o + 2 * bigbuf <= ws_size) {
    big = true;
    t1 = (bf16*)take(bigbuf);
    t2 = (bf16*)take(bigbuf);
  }

  // all weights -> bf16 transposed AND LN1, one launch (independent BW work)
  prep_kernel<<<26624 + 16384, 256, 0, stream>>>(
      w_in, w_out, mw1, mw2, mw3, w_inT, w_outT, mw1T, mw2T, mw3T,
      x, ln1g, ln1b, lnxB);

  // GEMM1 (pi)
  gemm256<0><<<256, 512, 0, stream>>>(lnxB, w_inT, b_in, nullptr, piB, 16384, 1024, 1024);

  // per-head gates + fused chunk-scan -> a,b,cA,cB ; chunk-state scan ; final pass
  heads_kernel<<<dim3(256, 16), 256, 0, stream>>>(piB, wz, bz, wh, bh, aB, bB, cA, cB);
  scan_phase2<<<16, 256, 0, stream>>>(h0, cA, cB, hst);
  scan_phase3<<<256, 128, 0, stream>>>(aB, bB, hst, out1, lnxB /*rnnB*/);

  // xr = x + rnn @ w_out + b_out   (written to out0)
  gemm256<2><<<256, 512, 0, stream>>>(lnxB, w_outT, b_out, x, out0, 16384, 1024, 1024);

  // LN2 -> MLP, final GEMM adds xr in place in out0
  ln_kernel<<<16384, 256, 0, stream>>>(out0, ln2g, ln2b, lnxB /*ln2B*/);
  if (big) {
    gemm256<1><<<1024, 512, 0, stream>>>(lnxB, mw1T, mb1, nullptr, t1, 16384, 4096, 1024);
    gemm256<1><<<1024, 512, 0, stream>>>(t1, mw2T, mb2, nullptr, t2, 16384, 4096, 4096);
    gemm256<2><<<256, 512, 0, stream>>>(t2, mw3T, mb3, out0, out0, 16384, 1024, 4096);
  } else {
    for (int mc = 0; mc < 4; ++mc) {
      const bf16* a3 = lnxB + (size_t)mc * 4096 * 1024;
      gemm256<1><<<256, 512, 0, stream>>>(a3, mw1T, mb1, nullptr, t1, 4096, 4096, 1024);
      gemm256<1><<<256, 512, 0, stream>>>(t1, mw2T, mb2, nullptr, t2, 4096, 4096, 4096);
      float* oc = out0 + (size_t)mc * 4096 * 1024;
      gemm128<2><<<256, 256, 0, stream>>>(t2, mw3T, mb3, oc, oc, 4096, 1024, 4096);
    }
  }
}